// Round 7
// baseline (514.447 us; speedup 1.0000x reference)
//
#include <hip/hip_runtime.h>
#include <cstdint>
#include <cstddef>

#define N_NODES 100000
#define E_EDGES 1600000
#define E_TOT   1700000
#define HEADS   8
#define C1      8
#define HC1     64
#define NCLS    3
#define HC2     24
#define IN_CH   500
#define NEG     0.2f

#define TILES   6250    /* 100000 / 16 */
#define NBLK    256

#define NPB     64                      /* nodes per bucket */
#define NBUCK   1563                    /* ceil(100000/64) */
#define BCAP    2048                    /* edges capacity per bucket (mean ~1088) */

typedef __attribute__((ext_vector_type(8))) _Float16 f16x8;
typedef __attribute__((ext_vector_type(4))) _Float16 f16x4;
typedef __attribute__((ext_vector_type(4))) float f32x4;

// ---------------- edge dtype detection (int32 vs int64 edge_index) -----------
__global__ void k_detect(const int* __restrict__ ei, int* __restrict__ flag) {
  int i = blockIdx.x * blockDim.x + threadIdx.x;   // 4096 threads
  bool nz = ei[2 * i + 1] != 0;
  if (__ballot(nz)) {
    if ((threadIdx.x & 63) == 0) atomicOr(flag, 1);
  }
}

__device__ __forceinline__ int edge_at(const int* __restrict__ ei, int idx, int mode) {
  return mode ? ei[idx] : ei[2 * idx];   // int64: low word
}

// ---------------- CSR build via bucket sort ----------------------------------
// Pass A: append (src<<6 | dst&63) to bucket dst>>6. Writes hit ~1563 hot
// bucket tails -> L2-coalesced (vs write-amplified random scatter).
__global__ void k_bucketA(const int* __restrict__ ei, const int* __restrict__ flag,
                          int* __restrict__ bcnt, unsigned* __restrict__ bstage) {
  int e = blockIdx.x * blockDim.x + threadIdx.x;
  if (e >= E_TOT) return;
  int mode = *flag;
  int s, d;
  if (e < E_EDGES) { s = edge_at(ei, e, mode); d = edge_at(ei, E_EDGES + e, mode); }
  else             { s = e - E_EDGES; d = s; }
  int b = d >> 6;
  int pos = atomicAdd(&bcnt[b], 1);
  if (pos < BCAP) bstage[(size_t)b * BCAP + pos] = ((unsigned)s << 6) | (unsigned)(d & 63);
}

// exclusive bases over 1563 bucket counts; rowptr[N] = total.
// Serial-scan structure (thread 0 scans 256 partials) - airtight by inspection.
__global__ void k_bscan(const int* __restrict__ bcnt, int* __restrict__ bbase,
                        int* __restrict__ rowptr) {
  __shared__ int psum[256];
  int tid = threadIdx.x;
  int tsum = 0;
#pragma unroll
  for (int j = 0; j < 7; ++j) {
    int i = tid * 7 + j;
    if (i < NBUCK) tsum += min(bcnt[i], BCAP);
  }
  psum[tid] = tsum;
  __syncthreads();
  if (tid == 0) {
    int run = 0;
    for (int t = 0; t < 256; ++t) { int v = psum[t]; psum[t] = run; run += v; }
    rowptr[N_NODES] = run;
  }
  __syncthreads();
  int run = psum[tid];
#pragma unroll
  for (int j = 0; j < 7; ++j) {
    int i = tid * 7 + j;
    if (i < NBUCK) { bbase[i] = run; run += min(bcnt[i], BCAP); }
  }
}

// Pass B: one block per bucket. LDS-stage edges, LDS-histogram 64 local dsts,
// serial scan (thread 0) -> rowptr, then scatter into contiguous esrc window.
__global__ __launch_bounds__(256) void k_bucketB(const unsigned* __restrict__ bstage,
    const int* __restrict__ bcnt, const int* __restrict__ bbase,
    int* __restrict__ rowptr, int* __restrict__ esrc) {
  __shared__ unsigned edges[BCAP];   // 8 KB
  __shared__ int lhist[NPB];
  __shared__ int lptr[NPB];
  const int b = blockIdx.x;
  const int tid = threadIdx.x;
  const int n = min(bcnt[b], BCAP);
  const int base = bbase[b];

  if (tid < NPB) lhist[tid] = 0;
  for (int i = tid; i < n; i += 256) edges[i] = bstage[(size_t)b * BCAP + i];
  __syncthreads();
  for (int i = tid; i < n; i += 256) atomicAdd(&lhist[(int)(edges[i] & 63u)], 1);
  __syncthreads();
  if (tid == 0) {                    // serial exclusive scan over 64 entries
    int run = base;
    for (int k = 0; k < NPB; ++k) { int v = lhist[k]; lptr[k] = run; run += v; }
  }
  __syncthreads();
  if (tid < NPB) {
    int node = b * NPB + tid;
    if (node < N_NODES) rowptr[node] = lptr[tid];
  }
  __syncthreads();                   // rowptr snapshot done BEFORE lptr mutates
  for (int i = tid; i < n; i += 256) {
    unsigned pk = edges[i];
    int pos = atomicAdd(&lptr[(int)(pk & 63u)], 1);
    if ((unsigned)pos < (unsigned)E_TOT) esrc[pos] = (int)(pk >> 6);
  }
}

// ---------------- W1 pre-convert to fp16 LDS-image ---------------------------
// Image layout == desired LDS layout: [col 0..127][k 0..511] fp16, row stride
// 1024B, XOR-swizzled byte ^= (col&7)<<4, k>=500 zero-padded. 128KB.
__global__ void k_wconv(const float* __restrict__ W1l, const float* __restrict__ W1r,
                        _Float16* __restrict__ Wimg) {
  int t = blockIdx.x * 256 + threadIdx.x;   // 65536 = 128*512
  int col = t >> 9, k = t & 511;
  float v = 0.f;
  if (k < IN_CH) v = (col < HC1) ? W1l[k * HC1 + col] : W1r[k * HC1 + (col - HC1)];
  int boff = (col * 1024 + k * 2) ^ ((col & 7) << 4);
  Wimg[boff >> 1] = (_Float16)v;
}

// ---------------- GEMM1: fp16 2-product MFMA, weight-stationary in LDS -------
#define ABASE 131072
#define ALO   16384

__global__ __launch_bounds__(512, 1) void k_gemm1(const float* __restrict__ x,
    const uint4* __restrict__ Wimg, float* __restrict__ xl, float* __restrict__ xr) {
  __shared__ char lds[163840];
  const int tid  = threadIdx.x;
  const int lane = tid & 63, wid = tid >> 6;
  const int lrow = lane & 15, kg = lane >> 4;
  const int colgrp = wid & 3;
  const int kw0 = (wid >> 2) * 8;

  // ---- copy W image (L2/L3-hot) into LDS, linear
#pragma unroll
  for (int i = 0; i < 16; ++i) {
    int idx = i * 512 + tid;
    uint4 v = Wimg[idx];
    *(uint4*)(lds + idx * 16) = v;
  }

  // ---- per-thread staging map (constant across tiles)
  int xoff[4], aoff[4], mode[4];
#pragma unroll
  for (int i = 0; i < 4; ++i) {
    int s = tid + i * 512;
    if (s < 2000) {
      int row = s / 125, c4 = s - row * 125;
      xoff[i] = row * 500 + c4 * 4;
      aoff[i] = (row * 1024 + c4 * 8) ^ ((row & 7) << 4);
      mode[i] = 0;
    } else {
      int p = s - 2000;           // 0..47
      int row = p / 3, j = p - row * 3;
      aoff[i] = (row * 1024 + 1000 + j * 8) ^ ((row & 7) << 4);
      xoff[i] = 0;
      mode[i] = 1;
    }
  }

  float4 rv[4];
  auto loadregs = [&](int tile) {
#pragma unroll
    for (int i = 0; i < 4; ++i)
      if (mode[i] == 0)
        rv[i] = *(const float4*)&x[(size_t)tile * 8000 + xoff[i]];
  };

  loadregs(blockIdx.x);
  __syncthreads();   // W table resident

  for (int tile = blockIdx.x; tile < TILES; tile += NBLK) {
    // ---- stage A: convert fp32 regs -> fp16 hi + (lo * 2048), swizzled LDS
#pragma unroll
    for (int i = 0; i < 4; ++i) {
      f16x4 h, l;
      if (mode[i] == 0) {
        float vals[4] = {rv[i].x, rv[i].y, rv[i].z, rv[i].w};
#pragma unroll
        for (int c = 0; c < 4; ++c) {
          _Float16 hh = (_Float16)vals[c];
          float r = vals[c] - (float)hh;
          h[c] = hh;
          l[c] = (_Float16)(r * 2048.f);
        }
      } else {
        h = (f16x4){0, 0, 0, 0}; l = (f16x4){0, 0, 0, 0};
      }
      *(f16x4*)(lds + ABASE + aoff[i]) = h;
      *(f16x4*)(lds + ABASE + ALO + aoff[i]) = l;
    }
    __syncthreads();   // A(t) visible
    if (tile + NBLK < TILES) loadregs(tile + NBLK);   // prefetch under compute

    // ---- compute: 8 K-windows x {2 A-frags, 2 B-frags, 4 MFMA}
    f32x4 acch[2], accl[2];
    acch[0] = (f32x4){0,0,0,0}; acch[1] = (f32x4){0,0,0,0};
    accl[0] = (f32x4){0,0,0,0}; accl[1] = (f32x4){0,0,0,0};
#pragma unroll
    for (int kw = 0; kw < 8; ++kw) {
      const int kwin = kw0 + kw;
      const int koff = kwin * 64 + kg * 16;
      int ao = (lrow * 1024 + koff) ^ ((lrow & 7) << 4);
      f16x8 ah = *(const f16x8*)(lds + ABASE + ao);
      f16x8 al = *(const f16x8*)(lds + ABASE + ALO + ao);
#pragma unroll
      for (int n = 0; n < 2; ++n) {
        int col = colgrp * 32 + n * 16 + lrow;
        int bo = (col * 1024 + koff) ^ ((col & 7) << 4);
        f16x8 b = *(const f16x8*)(lds + bo);
        acch[n] = __builtin_amdgcn_mfma_f32_16x16x32_f16(ah, b, acch[n], 0, 0, 0);
        accl[n] = __builtin_amdgcn_mfma_f32_16x16x32_f16(al, b, accl[n], 0, 0, 0);
      }
    }
    // ---- epilogue: v = acc_h + acc_l/2048; split-K combine via LDS
    float v[2][4];
#pragma unroll
    for (int n = 0; n < 2; ++n)
#pragma unroll
      for (int j = 0; j < 4; ++j)
        v[n][j] = acch[n][j] + accl[n][j] * 4.8828125e-4f;

    if (wid >= 4) {   // upper K-half: publish partials into A region (dead)
      char* p = lds + ABASE + ((wid - 4) * 64 + lane) * 32;
      *(float4*)p       = make_float4(v[0][0], v[0][1], v[0][2], v[0][3]);
      *(float4*)(p+16)  = make_float4(v[1][0], v[1][1], v[1][2], v[1][3]);
    }
    __syncthreads();
    if (wid < 4) {    // lower K-half: combine + store C
      const char* p = lds + ABASE + (wid * 64 + lane) * 32;
      float4 p0 = *(const float4*)p, p1 = *(const float4*)(p+16);
      v[0][0]+=p0.x; v[0][1]+=p0.y; v[0][2]+=p0.z; v[0][3]+=p0.w;
      v[1][0]+=p1.x; v[1][1]+=p1.y; v[1][2]+=p1.z; v[1][3]+=p1.w;
      float* dst = (colgrp < 2) ? xl : xr;
      const int bm0 = tile * 16;
#pragma unroll
      for (int n = 0; n < 2; ++n) {
        int cc = (colgrp * 32 + n * 16 + lrow) & 63;
#pragma unroll
        for (int j = 0; j < 4; ++j)
          dst[(size_t)(bm0 + kg * 4 + j) * HC1 + cc] = v[n][j];
      }
    }
    __syncthreads();  // partials consumed; A region free for next stage
  }
}

// ---------------- layer-1 edge pass: online segment softmax + aggregate ------
__global__ __launch_bounds__(256) void k_edge1(const float* __restrict__ xl1,
    const float* __restrict__ xr1, const float* __restrict__ att1,
    const float* __restrict__ b1, const int* __restrict__ rowptr,
    const int* __restrict__ esrc, float* __restrict__ hbuf) {
  int t = blockIdx.x * blockDim.x + threadIdx.x;   // exact grid: N*8
  int node = t >> 3, h = t & 7;
  const float4* xrp = (const float4*)(xr1 + (size_t)node * HC1 + h * C1);
  float4 xa = xrp[0], xb = xrp[1];
  float xrv[8] = {xa.x, xa.y, xa.z, xa.w, xb.x, xb.y, xb.z, xb.w};
  const float4* ap = (const float4*)(att1 + h * C1);
  float4 aa = ap[0], ab = ap[1];
  float av[8] = {aa.x, aa.y, aa.z, aa.w, ab.x, ab.y, ab.z, ab.w};

  float m = -INFINITY, s = 0.f;
  float acc[8];
#pragma unroll
  for (int c = 0; c < 8; ++c) acc[c] = 0.f;

  auto gather = [&](int sn, float* v) {
    const float4* p = (const float4*)(xl1 + (size_t)sn * HC1 + h * C1);
    float4 A = p[0], B = p[1];
    v[0]=A.x; v[1]=A.y; v[2]=A.z; v[3]=A.w; v[4]=B.x; v[5]=B.y; v[6]=B.z; v[7]=B.w;
  };
  auto process = [&](const float* v) {
    float logit = 0.f;
#pragma unroll
    for (int c = 0; c < 8; ++c) {
      float u = v[c] + xrv[c];
      u = (u > 0.f) ? u : NEG * u;
      logit = fmaf(u, av[c], logit);
    }
    float mn = fmaxf(m, logit);
    float so = __expf(m - mn);
    float p  = __expf(logit - mn);
    s = s * so + p;
#pragma unroll
    for (int c = 0; c < 8; ++c) acc[c] = fmaf(acc[c], so, p * v[c]);
    m = mn;
  };

  int beg = rowptr[node], end = rowptr[node + 1];
  int i = beg;
  for (; i + 1 < end; i += 2) {
    int sn0 = esrc[i], sn1 = esrc[i + 1];
    if ((unsigned)sn0 >= N_NODES) sn0 = node;   // defensive: never OOB
    if ((unsigned)sn1 >= N_NODES) sn1 = node;
    float v0[8], v1[8];
    gather(sn0, v0); gather(sn1, v1);
    process(v0); process(v1);
  }
  if (i < end) {
    int sn0 = esrc[i];
    if ((unsigned)sn0 >= N_NODES) sn0 = node;
    float v0[8]; gather(sn0, v0); process(v0);
  }

  float inv = (s > 0.f) ? 1.f / s : 0.f;        // defensive: no 0/0 NaN
  float o[8];
#pragma unroll
  for (int c = 0; c < 8; ++c) {
    float v = fmaf(acc[c], inv, b1[h * C1 + c]);
    o[c] = (v > 0.f) ? v : expm1f(v);    // ELU
  }
  float4* hp = (float4*)(hbuf + (size_t)node * HC1 + h * C1);
  hp[0] = make_float4(o[0], o[1], o[2], o[3]);
  hp[1] = make_float4(o[4], o[5], o[6], o[7]);
}

// ---------------- GEMM2: xl2 = h@W2l, xr2 = h@W2r  (64 -> 24 each) -----------
__global__ __launch_bounds__(256) void k_gemm2(const float* __restrict__ hbuf,
    const float* __restrict__ W2l, const float* __restrict__ W2r,
    float* __restrict__ xl2, float* __restrict__ xr2) {
  __shared__ float w[64][48];
  int tid = threadIdx.x;
  for (int i = tid; i < 64 * 48; i += 256) {
    int k = i / 48, j = i - k * 48;
    w[k][j] = (j < HC2) ? W2l[k * HC2 + j] : W2r[k * HC2 + (j - HC2)];
  }
  __syncthreads();
  int node = blockIdx.x * 256 + tid;
  if (node >= N_NODES) return;
  float acc[48];
#pragma unroll
  for (int j = 0; j < 48; ++j) acc[j] = 0.f;
  const float4* hp = (const float4*)(hbuf + (size_t)node * HC1);
  for (int k0 = 0; k0 < 64; k0 += 16) {
    float rv[16];
#pragma unroll
    for (int q = 0; q < 4; ++q) {
      float4 r4 = hp[k0 / 4 + q];
      rv[q*4+0] = r4.x; rv[q*4+1] = r4.y; rv[q*4+2] = r4.z; rv[q*4+3] = r4.w;
    }
#pragma unroll
    for (int kk = 0; kk < 16; ++kk) {
      float hv = rv[kk];
      const float4* wrow = (const float4*)&w[k0 + kk][0];
#pragma unroll
      for (int j4 = 0; j4 < 12; ++j4) {
        float4 wv = wrow[j4];
        acc[j4*4+0] = fmaf(hv, wv.x, acc[j4*4+0]);
        acc[j4*4+1] = fmaf(hv, wv.y, acc[j4*4+1]);
        acc[j4*4+2] = fmaf(hv, wv.z, acc[j4*4+2]);
        acc[j4*4+3] = fmaf(hv, wv.w, acc[j4*4+3]);
      }
    }
  }
  float4* lp = (float4*)(xl2 + (size_t)node * HC2);
  float4* rp = (float4*)(xr2 + (size_t)node * HC2);
#pragma unroll
  for (int j4 = 0; j4 < 6; ++j4) {
    lp[j4] = make_float4(acc[j4*4+0], acc[j4*4+1], acc[j4*4+2], acc[j4*4+3]);
    rp[j4] = make_float4(acc[24+j4*4+0], acc[24+j4*4+1], acc[24+j4*4+2], acc[24+j4*4+3]);
  }
}

// ---------------- layer-2 edge pass + head-mean + final softmax --------------
__global__ __launch_bounds__(256) void k_edge2(const float* __restrict__ xl2,
    const float* __restrict__ xr2, const float* __restrict__ att2,
    const float* __restrict__ b2, const int* __restrict__ rowptr,
    const int* __restrict__ esrc, float* __restrict__ out) {
  int t = blockIdx.x * blockDim.x + threadIdx.x;   // exact grid: N*8
  int node = t >> 3, h = t & 7;
  float xrv[3], av[3];
#pragma unroll
  for (int c = 0; c < 3; ++c) {
    xrv[c] = xr2[(size_t)node * HC2 + h * NCLS + c];
    av[c]  = att2[h * NCLS + c];
  }
  float m = -INFINITY, s = 0.f;
  float acc[3] = {0.f, 0.f, 0.f};

  auto process = [&](const float* v) {
    float logit = 0.f;
#pragma unroll
    for (int c = 0; c < 3; ++c) {
      float u = v[c] + xrv[c];
      u = (u > 0.f) ? u : NEG * u;
      logit = fmaf(u, av[c], logit);
    }
    float mn = fmaxf(m, logit);
    float so = __expf(m - mn);
    float p  = __expf(logit - mn);
    s = s * so + p;
#pragma unroll
    for (int c = 0; c < 3; ++c) acc[c] = fmaf(acc[c], so, p * v[c]);
    m = mn;
  };

  int beg = rowptr[node], end = rowptr[node + 1];
  int i = beg;
  for (; i + 1 < end; i += 2) {
    int sn0 = esrc[i], sn1 = esrc[i + 1];
    if ((unsigned)sn0 >= N_NODES) sn0 = node;
    if ((unsigned)sn1 >= N_NODES) sn1 = node;
    float v0[3], v1[3];
#pragma unroll
    for (int c = 0; c < 3; ++c) v0[c] = xl2[(size_t)sn0 * HC2 + h * NCLS + c];
#pragma unroll
    for (int c = 0; c < 3; ++c) v1[c] = xl2[(size_t)sn1 * HC2 + h * NCLS + c];
    process(v0); process(v1);
  }
  if (i < end) {
    int sn0 = esrc[i];
    if ((unsigned)sn0 >= N_NODES) sn0 = node;
    float v0[3];
#pragma unroll
    for (int c = 0; c < 3; ++c) v0[c] = xl2[(size_t)sn0 * HC2 + h * NCLS + c];
    process(v0);
  }

  float inv = (s > 0.f) ? 1.f / s : 0.f;
  float o[3];
#pragma unroll
  for (int c = 0; c < 3; ++c) o[c] = acc[c] * inv;
  // mean over 8 heads (8-lane group butterfly; grid exact so all lanes live)
#pragma unroll
  for (int off = 1; off < 8; off <<= 1) {
#pragma unroll
    for (int c = 0; c < 3; ++c) o[c] += __shfl_xor(o[c], off);
  }
  if (h < 3) {
    float z[3];
#pragma unroll
    for (int c = 0; c < 3; ++c) z[c] = o[c] * 0.125f + b2[c];
    float mx = fmaxf(fmaxf(z[0], z[1]), z[2]);
    float e0 = __expf(z[0] - mx), e1 = __expf(z[1] - mx), e2 = __expf(z[2] - mx);
    float sum = e0 + e1 + e2;
    float num = (h == 0) ? e0 : (h == 1) ? e1 : e2;
    out[(size_t)node * NCLS + h] = num / sum;
  }
}

// ---------------- launch -----------------------------------------------------
extern "C" void kernel_launch(void* const* d_in, const int* in_sizes, int n_in,
                              void* d_out, int out_size, void* d_ws, size_t ws_size,
                              hipStream_t stream) {
  (void)in_sizes; (void)n_in; (void)out_size; (void)ws_size;
  const float* x    = (const float*)d_in[0];
  const int*   ei   = (const int*)d_in[1];
  const float* W1l  = (const float*)d_in[2];
  const float* W1r  = (const float*)d_in[3];
  const float* att1 = (const float*)d_in[4];
  const float* b1   = (const float*)d_in[5];
  const float* W2l  = (const float*)d_in[6];
  const float* W2r  = (const float*)d_in[7];
  const float* att2 = (const float*)d_in[8];
  const float* b2   = (const float*)d_in[9];
  float* out = (float*)d_out;

  char* w = (char*)d_ws;
  float* xl1  = (float*)(w);                 // 25.6 MB (bstage overlays pre-gemm1)
  float* xr1  = (float*)(w + 25600000);      // 25.6 MB
  float* hbuf = (float*)(w + 51200000);      // 25.6 MB (W image lives here pre-edge1)
  float* xl2  = (float*)(w);                 // overlays xl1 (dead after edge1)
  float* xr2  = (float*)(w + 9600000);       // inside old xl1 region
  _Float16* Wimg = (_Float16*)(w + 51200000);          // 128 KB fp16 LDS-image
  unsigned* bstage = (unsigned*)(w);         // 12.8 MB, dead before gemm1 writes xl1
  char* ip = w + 76800000;
  int* rowptr = (int*)(ip);                  // 400004 B
  int* bcnt   = (int*)(ip + 400256);         // 6252 B
  int* flag   = (int*)(ip + 406508);         // 4 B (contiguous with bcnt for memset)
  int* bbase  = (int*)(ip + 406512);         // 6252 B
  int* esrc   = (int*)(ip + 412800);         // 6.8 MB -> total ~84.0 MB

  hipMemsetAsync(bcnt, 0, 6256, stream);     // bcnt + flag

  k_detect  <<<16, 256, 0, stream>>>(ei, flag);
  k_wconv   <<<256, 256, 0, stream>>>(W1l, W1r, Wimg);
  k_bucketA <<<(E_TOT + 255) / 256, 256, 0, stream>>>(ei, flag, bcnt, bstage);
  k_bscan   <<<1, 256, 0, stream>>>(bcnt, bbase, rowptr);
  k_bucketB <<<NBUCK, 256, 0, stream>>>(bstage, bcnt, bbase, rowptr, esrc);
  k_gemm1   <<<NBLK, 512, 0, stream>>>(x, (const uint4*)Wimg, xl1, xr1);
  k_edge1   <<<(N_NODES * HEADS) / 256, 256, 0, stream>>>(xl1, xr1, att1, b1, rowptr, esrc, hbuf);
  k_gemm2   <<<(N_NODES + 255) / 256, 256, 0, stream>>>(hbuf, W2l, W2r, xl2, xr2);
  k_edge2   <<<(N_NODES * HEADS) / 256, 256, 0, stream>>>(xl2, xr2, att2, b2, rowptr, esrc, out);
}

// Round 8
// 432.817 us; speedup vs baseline: 1.1886x; 1.1886x over previous
//
#include <hip/hip_runtime.h>
#include <cstdint>
#include <cstddef>

#define N_NODES 100000
#define E_EDGES 1600000
#define E_TOT   1700000
#define HEADS   8
#define C1      8
#define HC1     64
#define NCLS    3
#define HC2     24
#define IN_CH   500
#define NEG     0.2f

#define SEG     2048
#define NSEG    49      /* ceil(100000/2048) */
#define TILES   6250    /* 100000 / 16 */
#define NBLK    256

typedef __attribute__((ext_vector_type(8))) _Float16 f16x8;
typedef __attribute__((ext_vector_type(4))) _Float16 f16x4;
typedef __attribute__((ext_vector_type(4))) float f32x4;

// ---------------- edge dtype detection (int32 vs int64 edge_index) -----------
__global__ void k_detect(const int* __restrict__ ei, int* __restrict__ flag) {
  int i = blockIdx.x * blockDim.x + threadIdx.x;   // 4096 threads
  bool nz = ei[2 * i + 1] != 0;
  if (__ballot(nz)) {
    if ((threadIdx.x & 63) == 0) atomicOr(flag, 1);
  }
}

__device__ __forceinline__ int edge_at(const int* __restrict__ ei, int idx, int mode) {
  return mode ? ei[idx] : ei[2 * idx];   // int64: low word
}

// ---------------- CSR build (R5-proven structure) ----------------------------
__global__ void k_hist(const int* __restrict__ ei, const int* __restrict__ flag,
                       int* __restrict__ deg) {
  int e = blockIdx.x * blockDim.x + threadIdx.x;
  if (e >= E_TOT) return;
  int mode = *flag;
  int d = (e < E_EDGES) ? edge_at(ei, E_EDGES + e, mode) : (e - E_EDGES);
  atomicAdd(&deg[d], 1);
}

__global__ void k_seg_sum(const int* __restrict__ deg, int* __restrict__ segsum) {
  __shared__ int sh[256];
  int tid = threadIdx.x;
  int base = blockIdx.x * SEG;
  int sum = 0;
#pragma unroll
  for (int j = 0; j < 8; ++j) {
    int idx = base + j * 256 + tid;
    if (idx < N_NODES) sum += deg[idx];
  }
  sh[tid] = sum; __syncthreads();
  for (int off = 128; off > 0; off >>= 1) {
    if (tid < off) sh[tid] += sh[tid + off];
    __syncthreads();
  }
  if (tid == 0) segsum[blockIdx.x] = sh[0];
}

__global__ void k_scan_small(const int* __restrict__ segsum, int* __restrict__ segoff,
                             int* __restrict__ rowptr) {
  if (threadIdx.x == 0 && blockIdx.x == 0) {
    int run = 0;
    for (int s = 0; s < NSEG; ++s) { int t = segsum[s]; segoff[s] = run; run += t; }
    rowptr[N_NODES] = run;   // == E_TOT
  }
}

__global__ void k_seg_scan(const int* __restrict__ deg, const int* __restrict__ segoff,
                           int* __restrict__ rowptr, int* __restrict__ wptr) {
  __shared__ int sh[256];
  int tid = threadIdx.x;
  int idx0 = blockIdx.x * SEG + tid * 8;
  int v[8]; int tsum = 0;
#pragma unroll
  for (int j = 0; j < 8; ++j) {
    int idx = idx0 + j;
    v[j] = (idx < N_NODES) ? deg[idx] : 0;
    tsum += v[j];
  }
  sh[tid] = tsum; __syncthreads();
  for (int off = 1; off < 256; off <<= 1) {
    int add = (tid >= off) ? sh[tid - off] : 0;
    __syncthreads();
    sh[tid] += add;
    __syncthreads();
  }
  int run = segoff[blockIdx.x] + sh[tid] - tsum;   // exclusive prefix
#pragma unroll
  for (int j = 0; j < 8; ++j) {
    int idx = idx0 + j;
    if (idx < N_NODES) { rowptr[idx] = run; wptr[idx] = run; }
    run += v[j];
  }
}

__global__ void k_scatter(const int* __restrict__ ei, const int* __restrict__ flag,
                          int* __restrict__ wptr, int* __restrict__ esrc) {
  int e = blockIdx.x * blockDim.x + threadIdx.x;
  if (e >= E_TOT) return;
  int mode = *flag;
  int s, d;
  if (e < E_EDGES) { s = edge_at(ei, e, mode); d = edge_at(ei, E_EDGES + e, mode); }
  else             { s = e - E_EDGES; d = s; }
  int pos = atomicAdd(&wptr[d], 1);          // single atomic; no rowptr read
  __builtin_nontemporal_store(s, &esrc[pos]);
}

// ---------------- W1 pre-convert to fp16 LDS-image ---------------------------
// Image layout == desired LDS layout: [col 0..127][k 0..511] fp16, row stride
// 1024B, XOR-swizzled byte ^= (col&7)<<4, k>=500 zero-padded. 128KB.
__global__ void k_wconv(const float* __restrict__ W1l, const float* __restrict__ W1r,
                        _Float16* __restrict__ Wimg) {
  int t = blockIdx.x * 256 + threadIdx.x;   // 65536 = 128*512
  int col = t >> 9, k = t & 511;
  float v = 0.f;
  if (k < IN_CH) v = (col < HC1) ? W1l[k * HC1 + col] : W1r[k * HC1 + (col - HC1)];
  int boff = (col * 1024 + k * 2) ^ ((col & 7) << 4);
  Wimg[boff >> 1] = (_Float16)v;
}

// ---------------- GEMM1: fp16 2-product MFMA, weight-stationary in LDS -------
#define ABASE 131072
#define ALO   16384

__global__ __launch_bounds__(512, 1) void k_gemm1(const float* __restrict__ x,
    const uint4* __restrict__ Wimg, float* __restrict__ xl, float* __restrict__ xr) {
  __shared__ char lds[163840];
  const int tid  = threadIdx.x;
  const int lane = tid & 63, wid = tid >> 6;
  const int lrow = lane & 15, kg = lane >> 4;
  const int colgrp = wid & 3;
  const int kw0 = (wid >> 2) * 8;

  // ---- copy W image (L2/L3-hot) into LDS, linear
#pragma unroll
  for (int i = 0; i < 16; ++i) {
    int idx = i * 512 + tid;
    uint4 v = Wimg[idx];
    *(uint4*)(lds + idx * 16) = v;
  }

  // ---- per-thread staging map (constant across tiles)
  int xoff[4], aoff[4], mode[4];
#pragma unroll
  for (int i = 0; i < 4; ++i) {
    int s = tid + i * 512;
    if (s < 2000) {
      int row = s / 125, c4 = s - row * 125;
      xoff[i] = row * 500 + c4 * 4;
      aoff[i] = (row * 1024 + c4 * 8) ^ ((row & 7) << 4);
      mode[i] = 0;
    } else {
      int p = s - 2000;           // 0..47
      int row = p / 3, j = p - row * 3;
      aoff[i] = (row * 1024 + 1000 + j * 8) ^ ((row & 7) << 4);
      xoff[i] = 0;
      mode[i] = 1;
    }
  }

  float4 rv[4];
  auto loadregs = [&](int tile) {
#pragma unroll
    for (int i = 0; i < 4; ++i)
      if (mode[i] == 0)
        rv[i] = *(const float4*)&x[(size_t)tile * 8000 + xoff[i]];
  };

  loadregs(blockIdx.x);
  __syncthreads();   // W table resident

  for (int tile = blockIdx.x; tile < TILES; tile += NBLK) {
    // ---- stage A: convert fp32 regs -> fp16 hi + (lo * 2048), swizzled LDS
#pragma unroll
    for (int i = 0; i < 4; ++i) {
      f16x4 h, l;
      if (mode[i] == 0) {
        float vals[4] = {rv[i].x, rv[i].y, rv[i].z, rv[i].w};
#pragma unroll
        for (int c = 0; c < 4; ++c) {
          _Float16 hh = (_Float16)vals[c];
          float r = vals[c] - (float)hh;
          h[c] = hh;
          l[c] = (_Float16)(r * 2048.f);
        }
      } else {
        h = (f16x4){0, 0, 0, 0}; l = (f16x4){0, 0, 0, 0};
      }
      *(f16x4*)(lds + ABASE + aoff[i]) = h;
      *(f16x4*)(lds + ABASE + ALO + aoff[i]) = l;
    }
    __syncthreads();   // A(t) visible
    if (tile + NBLK < TILES) loadregs(tile + NBLK);   // prefetch under compute

    // ---- compute: 8 K-windows x {2 A-frags, 2 B-frags, 4 MFMA}
    f32x4 acch[2], accl[2];
    acch[0] = (f32x4){0,0,0,0}; acch[1] = (f32x4){0,0,0,0};
    accl[0] = (f32x4){0,0,0,0}; accl[1] = (f32x4){0,0,0,0};
#pragma unroll
    for (int kw = 0; kw < 8; ++kw) {
      const int kwin = kw0 + kw;
      const int koff = kwin * 64 + kg * 16;
      int ao = (lrow * 1024 + koff) ^ ((lrow & 7) << 4);
      f16x8 ah = *(const f16x8*)(lds + ABASE + ao);
      f16x8 al = *(const f16x8*)(lds + ABASE + ALO + ao);
#pragma unroll
      for (int n = 0; n < 2; ++n) {
        int col = colgrp * 32 + n * 16 + lrow;
        int bo = (col * 1024 + koff) ^ ((col & 7) << 4);
        f16x8 b = *(const f16x8*)(lds + bo);
        acch[n] = __builtin_amdgcn_mfma_f32_16x16x32_f16(ah, b, acch[n], 0, 0, 0);
        accl[n] = __builtin_amdgcn_mfma_f32_16x16x32_f16(al, b, accl[n], 0, 0, 0);
      }
    }
    // ---- epilogue: v = acc_h + acc_l/2048; split-K combine via LDS
    float v[2][4];
#pragma unroll
    for (int n = 0; n < 2; ++n)
#pragma unroll
      for (int j = 0; j < 4; ++j)
        v[n][j] = acch[n][j] + accl[n][j] * 4.8828125e-4f;

    if (wid >= 4) {   // upper K-half: publish partials into A region (dead)
      char* p = lds + ABASE + ((wid - 4) * 64 + lane) * 32;
      *(float4*)p       = make_float4(v[0][0], v[0][1], v[0][2], v[0][3]);
      *(float4*)(p+16)  = make_float4(v[1][0], v[1][1], v[1][2], v[1][3]);
    }
    __syncthreads();
    if (wid < 4) {    // lower K-half: combine + store C
      const char* p = lds + ABASE + (wid * 64 + lane) * 32;
      float4 p0 = *(const float4*)p, p1 = *(const float4*)(p+16);
      v[0][0]+=p0.x; v[0][1]+=p0.y; v[0][2]+=p0.z; v[0][3]+=p0.w;
      v[1][0]+=p1.x; v[1][1]+=p1.y; v[1][2]+=p1.z; v[1][3]+=p1.w;
      float* dst = (colgrp < 2) ? xl : xr;
      const int bm0 = tile * 16;
#pragma unroll
      for (int n = 0; n < 2; ++n) {
        int cc = (colgrp * 32 + n * 16 + lrow) & 63;
#pragma unroll
        for (int j = 0; j < 4; ++j)
          dst[(size_t)(bm0 + kg * 4 + j) * HC1 + cc] = v[n][j];
      }
    }
    __syncthreads();  // partials consumed; A region free for next stage
  }
}

// ---------------- layer-1 edge pass: online segment softmax + aggregate ------
// thread = (node, head); 8 consecutive lanes = 8 heads of one node.
// 4-way edge unroll: four independent row gathers in flight.
__global__ __launch_bounds__(256) void k_edge1(const float* __restrict__ xl1,
    const float* __restrict__ xr1, const float* __restrict__ att1,
    const float* __restrict__ b1, const int* __restrict__ rowptr,
    const int* __restrict__ esrc, float* __restrict__ hbuf) {
  int t = blockIdx.x * blockDim.x + threadIdx.x;   // exact grid: N*8
  int node = t >> 3, h = t & 7;
  const float4* xrp = (const float4*)(xr1 + (size_t)node * HC1 + h * C1);
  float4 xa = xrp[0], xb = xrp[1];
  float xrv[8] = {xa.x, xa.y, xa.z, xa.w, xb.x, xb.y, xb.z, xb.w};
  const float4* ap = (const float4*)(att1 + h * C1);
  float4 aa = ap[0], ab = ap[1];
  float av[8] = {aa.x, aa.y, aa.z, aa.w, ab.x, ab.y, ab.z, ab.w};

  float m = -INFINITY, s = 0.f;
  float acc[8];
#pragma unroll
  for (int c = 0; c < 8; ++c) acc[c] = 0.f;

  auto gather = [&](int sn, float* v) {
    const float4* p = (const float4*)(xl1 + (size_t)sn * HC1 + h * C1);
    float4 A = p[0], B = p[1];
    v[0]=A.x; v[1]=A.y; v[2]=A.z; v[3]=A.w; v[4]=B.x; v[5]=B.y; v[6]=B.z; v[7]=B.w;
  };
  auto process = [&](const float* v) {
    float logit = 0.f;
#pragma unroll
    for (int c = 0; c < 8; ++c) {
      float u = v[c] + xrv[c];
      u = (u > 0.f) ? u : NEG * u;
      logit = fmaf(u, av[c], logit);
    }
    float mn = fmaxf(m, logit);
    float so = __expf(m - mn);
    float p  = __expf(logit - mn);
    s = s * so + p;
#pragma unroll
    for (int c = 0; c < 8; ++c) acc[c] = fmaf(acc[c], so, p * v[c]);
    m = mn;
  };

  int beg = rowptr[node], end = rowptr[node + 1];
  int i = beg;
  for (; i + 3 < end; i += 4) {
    int sn0 = esrc[i], sn1 = esrc[i+1], sn2 = esrc[i+2], sn3 = esrc[i+3];
    if ((unsigned)sn0 >= N_NODES) sn0 = node;
    if ((unsigned)sn1 >= N_NODES) sn1 = node;
    if ((unsigned)sn2 >= N_NODES) sn2 = node;
    if ((unsigned)sn3 >= N_NODES) sn3 = node;
    float v0[8], v1[8], v2[8], v3[8];
    gather(sn0, v0); gather(sn1, v1); gather(sn2, v2); gather(sn3, v3);
    process(v0); process(v1); process(v2); process(v3);
  }
  for (; i < end; ++i) {
    int sn0 = esrc[i];
    if ((unsigned)sn0 >= N_NODES) sn0 = node;
    float v0[8]; gather(sn0, v0); process(v0);
  }

  float inv = (s > 0.f) ? 1.f / s : 0.f;
  float o[8];
#pragma unroll
  for (int c = 0; c < 8; ++c) {
    float v = fmaf(acc[c], inv, b1[h * C1 + c]);
    o[c] = (v > 0.f) ? v : expm1f(v);    // ELU
  }
  float4* hp = (float4*)(hbuf + (size_t)node * HC1 + h * C1);
  hp[0] = make_float4(o[0], o[1], o[2], o[3]);
  hp[1] = make_float4(o[4], o[5], o[6], o[7]);
}

// ---------------- GEMM2: xl2 = h@W2l, xr2 = h@W2r  (64 -> 24 each) -----------
__global__ __launch_bounds__(256) void k_gemm2(const float* __restrict__ hbuf,
    const float* __restrict__ W2l, const float* __restrict__ W2r,
    float* __restrict__ xl2, float* __restrict__ xr2) {
  __shared__ float w[64][48];
  int tid = threadIdx.x;
  for (int i = tid; i < 64 * 48; i += 256) {
    int k = i / 48, j = i - k * 48;
    w[k][j] = (j < HC2) ? W2l[k * HC2 + j] : W2r[k * HC2 + (j - HC2)];
  }
  __syncthreads();
  int node = blockIdx.x * 256 + tid;
  if (node >= N_NODES) return;
  float acc[48];
#pragma unroll
  for (int j = 0; j < 48; ++j) acc[j] = 0.f;
  const float4* hp = (const float4*)(hbuf + (size_t)node * HC1);
  for (int k0 = 0; k0 < 64; k0 += 16) {
    float rv[16];
#pragma unroll
    for (int q = 0; q < 4; ++q) {
      float4 r4 = hp[k0 / 4 + q];
      rv[q*4+0] = r4.x; rv[q*4+1] = r4.y; rv[q*4+2] = r4.z; rv[q*4+3] = r4.w;
    }
#pragma unroll
    for (int kk = 0; kk < 16; ++kk) {
      float hv = rv[kk];
      const float4* wrow = (const float4*)&w[k0 + kk][0];
#pragma unroll
      for (int j4 = 0; j4 < 12; ++j4) {
        float4 wv = wrow[j4];
        acc[j4*4+0] = fmaf(hv, wv.x, acc[j4*4+0]);
        acc[j4*4+1] = fmaf(hv, wv.y, acc[j4*4+1]);
        acc[j4*4+2] = fmaf(hv, wv.z, acc[j4*4+2]);
        acc[j4*4+3] = fmaf(hv, wv.w, acc[j4*4+3]);
      }
    }
  }
  float4* lp = (float4*)(xl2 + (size_t)node * HC2);
  float4* rp = (float4*)(xr2 + (size_t)node * HC2);
#pragma unroll
  for (int j4 = 0; j4 < 6; ++j4) {
    lp[j4] = make_float4(acc[j4*4+0], acc[j4*4+1], acc[j4*4+2], acc[j4*4+3]);
    rp[j4] = make_float4(acc[24+j4*4+0], acc[24+j4*4+1], acc[24+j4*4+2], acc[24+j4*4+3]);
  }
}

// ---------------- layer-2 edge pass + head-mean + final softmax --------------
__global__ __launch_bounds__(256) void k_edge2(const float* __restrict__ xl2,
    const float* __restrict__ xr2, const float* __restrict__ att2,
    const float* __restrict__ b2, const int* __restrict__ rowptr,
    const int* __restrict__ esrc, float* __restrict__ out) {
  int t = blockIdx.x * blockDim.x + threadIdx.x;   // exact grid: N*8
  int node = t >> 3, h = t & 7;
  float xrv[3], av[3];
#pragma unroll
  for (int c = 0; c < 3; ++c) {
    xrv[c] = xr2[(size_t)node * HC2 + h * NCLS + c];
    av[c]  = att2[h * NCLS + c];
  }
  float m = -INFINITY, s = 0.f;
  float acc[3] = {0.f, 0.f, 0.f};

  auto process = [&](const float* v) {
    float logit = 0.f;
#pragma unroll
    for (int c = 0; c < 3; ++c) {
      float u = v[c] + xrv[c];
      u = (u > 0.f) ? u : NEG * u;
      logit = fmaf(u, av[c], logit);
    }
    float mn = fmaxf(m, logit);
    float so = __expf(m - mn);
    float p  = __expf(logit - mn);
    s = s * so + p;
#pragma unroll
    for (int c = 0; c < 3; ++c) acc[c] = fmaf(acc[c], so, p * v[c]);
    m = mn;
  };

  int beg = rowptr[node], end = rowptr[node + 1];
  int i = beg;
  for (; i + 1 < end; i += 2) {
    int sn0 = esrc[i], sn1 = esrc[i + 1];
    if ((unsigned)sn0 >= N_NODES) sn0 = node;
    if ((unsigned)sn1 >= N_NODES) sn1 = node;
    float v0[3], v1[3];
#pragma unroll
    for (int c = 0; c < 3; ++c) v0[c] = xl2[(size_t)sn0 * HC2 + h * NCLS + c];
#pragma unroll
    for (int c = 0; c < 3; ++c) v1[c] = xl2[(size_t)sn1 * HC2 + h * NCLS + c];
    process(v0); process(v1);
  }
  if (i < end) {
    int sn0 = esrc[i];
    if ((unsigned)sn0 >= N_NODES) sn0 = node;
    float v0[3];
#pragma unroll
    for (int c = 0; c < 3; ++c) v0[c] = xl2[(size_t)sn0 * HC2 + h * NCLS + c];
    process(v0);
  }

  float inv = (s > 0.f) ? 1.f / s : 0.f;
  float o[3];
#pragma unroll
  for (int c = 0; c < 3; ++c) o[c] = acc[c] * inv;
  // mean over 8 heads (8-lane group butterfly; grid exact so all lanes live)
#pragma unroll
  for (int off = 1; off < 8; off <<= 1) {
#pragma unroll
    for (int c = 0; c < 3; ++c) o[c] += __shfl_xor(o[c], off);
  }
  if (h < 3) {
    float z[3];
#pragma unroll
    for (int c = 0; c < 3; ++c) z[c] = o[c] * 0.125f + b2[c];
    float mx = fmaxf(fmaxf(z[0], z[1]), z[2]);
    float e0 = __expf(z[0] - mx), e1 = __expf(z[1] - mx), e2 = __expf(z[2] - mx);
    float sum = e0 + e1 + e2;
    float num = (h == 0) ? e0 : (h == 1) ? e1 : e2;
    out[(size_t)node * NCLS + h] = num / sum;
  }
}

// ---------------- launch -----------------------------------------------------
extern "C" void kernel_launch(void* const* d_in, const int* in_sizes, int n_in,
                              void* d_out, int out_size, void* d_ws, size_t ws_size,
                              hipStream_t stream) {
  (void)in_sizes; (void)n_in; (void)out_size; (void)ws_size;
  const float* x    = (const float*)d_in[0];
  const int*   ei   = (const int*)d_in[1];
  const float* W1l  = (const float*)d_in[2];
  const float* W1r  = (const float*)d_in[3];
  const float* att1 = (const float*)d_in[4];
  const float* b1   = (const float*)d_in[5];
  const float* W2l  = (const float*)d_in[6];
  const float* W2r  = (const float*)d_in[7];
  const float* att2 = (const float*)d_in[8];
  const float* b2   = (const float*)d_in[9];
  float* out = (float*)d_out;

  char* w = (char*)d_ws;
  float* xl1  = (float*)(w);                 // 25.6 MB
  float* xr1  = (float*)(w + 25600000);      // 25.6 MB
  float* hbuf = (float*)(w + 51200000);      // 25.6 MB (W image lives here pre-edge1)
  float* xl2  = (float*)(w);                 // overlays xl1 (dead after edge1)
  float* xr2  = (float*)(w + 9600000);       // inside old xl1 region
  _Float16* Wimg = (_Float16*)(w + 51200000);          // 128 KB fp16 LDS-image
  char* ip = w + 76800000;
  int* deg    = (int*)(ip);                  // 400000 B
  int* wptr   = (int*)(ip + 400000);         // 400000 B (write cursors)
  int* rowptr = (int*)(ip + 800000);         // 400004 B
  int* segsum = (int*)(ip + 1200256);
  int* segoff = (int*)(ip + 1200512);
  int* flag   = (int*)(ip + 1200768);
  int* esrc   = (int*)(ip + 1201024);        // 6.8 MB  -> total ~84.8 MB

  hipMemsetAsync(deg, 0, 400000, stream);
  hipMemsetAsync(flag, 0, 4, stream);

  k_detect   <<<16, 256, 0, stream>>>(ei, flag);
  k_wconv    <<<256, 256, 0, stream>>>(W1l, W1r, Wimg);
  k_hist     <<<(E_TOT + 255) / 256, 256, 0, stream>>>(ei, flag, deg);
  k_seg_sum  <<<NSEG, 256, 0, stream>>>(deg, segsum);
  k_scan_small<<<1, 64, 0, stream>>>(segsum, segoff, rowptr);
  k_seg_scan <<<NSEG, 256, 0, stream>>>(deg, segoff, rowptr, wptr);
  k_scatter  <<<(E_TOT + 255) / 256, 256, 0, stream>>>(ei, flag, wptr, esrc);
  k_gemm1    <<<NBLK, 512, 0, stream>>>(x, (const uint4*)Wimg, xl1, xr1);
  k_edge1    <<<(N_NODES * HEADS) / 256, 256, 0, stream>>>(xl1, xr1, att1, b1, rowptr, esrc, hbuf);
  k_gemm2    <<<(N_NODES + 255) / 256, 256, 0, stream>>>(hbuf, W2l, W2r, xl2, xr2);
  k_edge2    <<<(N_NODES * HEADS) / 256, 256, 0, stream>>>(xl2, xr2, att2, b2, rowptr, esrc, out);
}

// Round 11
// 390.452 us; speedup vs baseline: 1.3176x; 1.1085x over previous
//
#include <hip/hip_runtime.h>
#include <cstdint>
#include <cstddef>

#define N_NODES 100000
#define E_EDGES 1600000
#define E_TOT   1700000
#define HEADS   8
#define C1      8
#define HC1     64
#define NCLS    3
#define HC2     24
#define IN_CH   500
#define NEG     0.2f

#define SEG     2048
#define NSEG    49      /* ceil(100000/2048) */
#define TILES   6250    /* 100000 / 16 */
#define NBLK    256

typedef __attribute__((ext_vector_type(8))) _Float16 f16x8;
typedef __attribute__((ext_vector_type(4))) _Float16 f16x4;
typedef __attribute__((ext_vector_type(4))) float f32x4;

// ---------------- edge dtype detection (int32 vs int64 edge_index) -----------
__global__ void k_detect(const int* __restrict__ ei, int* __restrict__ flag) {
  int i = blockIdx.x * blockDim.x + threadIdx.x;   // 4096 threads
  bool nz = ei[2 * i + 1] != 0;
  if (__ballot(nz)) {
    if ((threadIdx.x & 63) == 0) atomicOr(flag, 1);
  }
}

__device__ __forceinline__ int edge_at(const int* __restrict__ ei, int idx, int mode) {
  return mode ? ei[idx] : ei[2 * idx];   // int64: low word
}

// ---------------- CSR build (R5-proven, tripwire-stable) ---------------------
__global__ void k_hist(const int* __restrict__ ei, const int* __restrict__ flag,
                       int* __restrict__ deg) {
  int e = blockIdx.x * blockDim.x + threadIdx.x;
  if (e >= E_TOT) return;
  int mode = *flag;
  int d = (e < E_EDGES) ? edge_at(ei, E_EDGES + e, mode) : (e - E_EDGES);
  atomicAdd(&deg[d], 1);
}

__global__ void k_seg_sum(const int* __restrict__ deg, int* __restrict__ segsum) {
  __shared__ int sh[256];
  int tid = threadIdx.x;
  int base = blockIdx.x * SEG;
  int sum = 0;
#pragma unroll
  for (int j = 0; j < 8; ++j) {
    int idx = base + j * 256 + tid;
    if (idx < N_NODES) sum += deg[idx];
  }
  sh[tid] = sum; __syncthreads();
  for (int off = 128; off > 0; off >>= 1) {
    if (tid < off) sh[tid] += sh[tid + off];
    __syncthreads();
  }
  if (tid == 0) segsum[blockIdx.x] = sh[0];
}

__global__ void k_scan_small(const int* __restrict__ segsum, int* __restrict__ segoff,
                             int* __restrict__ rowptr) {
  if (threadIdx.x == 0 && blockIdx.x == 0) {
    int run = 0;
    for (int s = 0; s < NSEG; ++s) { int t = segsum[s]; segoff[s] = run; run += t; }
    rowptr[N_NODES] = run;   // == E_TOT
  }
}

__global__ void k_seg_scan(const int* __restrict__ deg, const int* __restrict__ segoff,
                           int* __restrict__ rowptr) {
  __shared__ int sh[256];
  int tid = threadIdx.x;
  int idx0 = blockIdx.x * SEG + tid * 8;
  int v[8]; int tsum = 0;
#pragma unroll
  for (int j = 0; j < 8; ++j) {
    int idx = idx0 + j;
    v[j] = (idx < N_NODES) ? deg[idx] : 0;
    tsum += v[j];
  }
  sh[tid] = tsum; __syncthreads();
  for (int off = 1; off < 256; off <<= 1) {
    int add = (tid >= off) ? sh[tid - off] : 0;
    __syncthreads();
    sh[tid] += add;
    __syncthreads();
  }
  int run = segoff[blockIdx.x] + sh[tid] - tsum;   // exclusive prefix
#pragma unroll
  for (int j = 0; j < 8; ++j) {
    int idx = idx0 + j;
    if (idx < N_NODES) rowptr[idx] = run;
    run += v[j];
  }
}

__global__ void k_scatter(const int* __restrict__ ei, const int* __restrict__ flag,
                          const int* __restrict__ rowptr, int* __restrict__ cnt,
                          int* __restrict__ esrc) {
  int e = blockIdx.x * blockDim.x + threadIdx.x;
  if (e >= E_TOT) return;
  int mode = *flag;
  int s, d;
  if (e < E_EDGES) { s = edge_at(ei, e, mode); d = edge_at(ei, E_EDGES + e, mode); }
  else             { s = e - E_EDGES; d = s; }
  int pos = rowptr[d] + atomicAdd(&cnt[d], 1);
  esrc[pos] = s;
}

// ---------------- W1 pre-convert to fp16 LDS-image ---------------------------
// Image layout == desired LDS layout: [col 0..127][k 0..511] fp16, row stride
// 1024B, XOR-swizzled byte ^= (col&7)<<4, k>=500 zero-padded. 128KB.
__global__ void k_wconv(const float* __restrict__ W1l, const float* __restrict__ W1r,
                        _Float16* __restrict__ Wimg) {
  int t = blockIdx.x * 256 + threadIdx.x;   // 65536 = 128*512
  int col = t >> 9, k = t & 511;
  float v = 0.f;
  if (k < IN_CH) v = (col < HC1) ? W1l[k * HC1 + col] : W1r[k * HC1 + (col - HC1)];
  int boff = (col * 1024 + k * 2) ^ ((col & 7) << 4);
  Wimg[boff >> 1] = (_Float16)v;
}

// ---------------- GEMM1: fp16 2-product MFMA, weight-stationary in LDS -------
// RACE FIX (R10 post-mortem): a __syncthreads() now separates the MFMA loop
// (which READS the A region) from the split-K partial publish (which WRITES
// the A region). Without it, fast upper waves corrupted slow lower waves'
// A-hi fragments -> fp16 NaN patterns -> NaN output (nondeterministic:
// passed R5/R7/R8 by luck, failed R6/R9/R10).
#define ABASE 131072
#define ALO   16384

__global__ __launch_bounds__(512, 1) void k_gemm1(const float* __restrict__ x,
    const uint4* __restrict__ Wimg, float* __restrict__ xl, float* __restrict__ xr) {
  __shared__ char lds[163840];
  const int tid  = threadIdx.x;
  const int lane = tid & 63, wid = tid >> 6;
  const int lrow = lane & 15, kg = lane >> 4;
  const int colgrp = wid & 3;
  const int kw0 = (wid >> 2) * 8;

  // ---- copy W image (L2/L3-hot) into LDS, linear
#pragma unroll
  for (int i = 0; i < 16; ++i) {
    int idx = i * 512 + tid;
    uint4 v = Wimg[idx];
    *(uint4*)(lds + idx * 16) = v;
  }

  // ---- per-thread staging map (constant across tiles)
  int xoff[4], aoff[4], mode[4];
#pragma unroll
  for (int i = 0; i < 4; ++i) {
    int s = tid + i * 512;
    if (s < 2000) {
      int row = s / 125, c4 = s - row * 125;
      xoff[i] = row * 500 + c4 * 4;
      aoff[i] = (row * 1024 + c4 * 8) ^ ((row & 7) << 4);
      mode[i] = 0;
    } else {
      int p = s - 2000;           // 0..47
      int row = p / 3, j = p - row * 3;
      aoff[i] = (row * 1024 + 1000 + j * 8) ^ ((row & 7) << 4);
      xoff[i] = 0;
      mode[i] = 1;
    }
  }

  float4 rv[4];
  auto loadregs = [&](int tile) {
#pragma unroll
    for (int i = 0; i < 4; ++i)
      if (mode[i] == 0)
        rv[i] = *(const float4*)&x[(size_t)tile * 8000 + xoff[i]];
  };

  loadregs(blockIdx.x);
  __syncthreads();   // W table resident

  for (int tile = blockIdx.x; tile < TILES; tile += NBLK) {
    // ---- stage A: convert fp32 regs -> fp16 hi + (lo * 2048), swizzled LDS
#pragma unroll
    for (int i = 0; i < 4; ++i) {
      f16x4 h, l;
      if (mode[i] == 0) {
        float vals[4] = {rv[i].x, rv[i].y, rv[i].z, rv[i].w};
#pragma unroll
        for (int c = 0; c < 4; ++c) {
          _Float16 hh = (_Float16)vals[c];
          float r = vals[c] - (float)hh;
          h[c] = hh;
          l[c] = (_Float16)(r * 2048.f);
        }
      } else {
        h = (f16x4){0, 0, 0, 0}; l = (f16x4){0, 0, 0, 0};
      }
      *(f16x4*)(lds + ABASE + aoff[i]) = h;
      *(f16x4*)(lds + ABASE + ALO + aoff[i]) = l;
    }
    __syncthreads();   // A(t) visible
    if (tile + NBLK < TILES) loadregs(tile + NBLK);   // prefetch under compute

    // ---- compute: 8 K-windows x {2 A-frags, 2 B-frags, 4 MFMA}
    f32x4 acch[2], accl[2];
    acch[0] = (f32x4){0,0,0,0}; acch[1] = (f32x4){0,0,0,0};
    accl[0] = (f32x4){0,0,0,0}; accl[1] = (f32x4){0,0,0,0};
#pragma unroll
    for (int kw = 0; kw < 8; ++kw) {
      const int kwin = kw0 + kw;
      const int koff = kwin * 64 + kg * 16;
      int ao = (lrow * 1024 + koff) ^ ((lrow & 7) << 4);
      f16x8 ah = *(const f16x8*)(lds + ABASE + ao);
      f16x8 al = *(const f16x8*)(lds + ABASE + ALO + ao);
#pragma unroll
      for (int n = 0; n < 2; ++n) {
        int col = colgrp * 32 + n * 16 + lrow;
        int bo = (col * 1024 + koff) ^ ((col & 7) << 4);
        f16x8 b = *(const f16x8*)(lds + bo);
        acch[n] = __builtin_amdgcn_mfma_f32_16x16x32_f16(ah, b, acch[n], 0, 0, 0);
        accl[n] = __builtin_amdgcn_mfma_f32_16x16x32_f16(al, b, accl[n], 0, 0, 0);
      }
    }
    // ---- epilogue: v = acc_h + acc_l/2048; split-K combine via LDS
    float v[2][4];
#pragma unroll
    for (int n = 0; n < 2; ++n)
#pragma unroll
      for (int j = 0; j < 4; ++j)
        v[n][j] = acch[n][j] + accl[n][j] * 4.8828125e-4f;

    __syncthreads();  // RACE FIX: all waves done READING A region before reuse

    if (wid >= 4) {   // upper K-half: publish partials into A region (dead now)
      char* p = lds + ABASE + ((wid - 4) * 64 + lane) * 32;
      *(float4*)p       = make_float4(v[0][0], v[0][1], v[0][2], v[0][3]);
      *(float4*)(p+16)  = make_float4(v[1][0], v[1][1], v[1][2], v[1][3]);
    }
    __syncthreads();
    if (wid < 4) {    // lower K-half: combine + store C
      const char* p = lds + ABASE + (wid * 64 + lane) * 32;
      float4 p0 = *(const float4*)p, p1 = *(const float4*)(p+16);
      v[0][0]+=p0.x; v[0][1]+=p0.y; v[0][2]+=p0.z; v[0][3]+=p0.w;
      v[1][0]+=p1.x; v[1][1]+=p1.y; v[1][2]+=p1.z; v[1][3]+=p1.w;
      float* dst = (colgrp < 2) ? xl : xr;
      const int bm0 = tile * 16;
#pragma unroll
      for (int n = 0; n < 2; ++n) {
        int cc = (colgrp * 32 + n * 16 + lrow) & 63;
#pragma unroll
        for (int j = 0; j < 4; ++j)
          dst[(size_t)(bm0 + kg * 4 + j) * HC1 + cc] = v[n][j];
      }
    }
    __syncthreads();  // partials consumed; A region free for next stage
  }
}

// ---------------- layer-1 edge pass: online segment softmax + aggregate ------
// thread = (node, head); 8 consecutive lanes = 8 heads of one node.
// 2-way edge unroll (R5-proven; 4-way regressed in R8).
__global__ __launch_bounds__(256) void k_edge1(const float* __restrict__ xl1,
    const float* __restrict__ xr1, const float* __restrict__ att1,
    const float* __restrict__ b1, const int* __restrict__ rowptr,
    const int* __restrict__ esrc, float* __restrict__ hbuf) {
  int t = blockIdx.x * blockDim.x + threadIdx.x;   // exact grid: N*8
  int node = t >> 3, h = t & 7;
  const float4* xrp = (const float4*)(xr1 + (size_t)node * HC1 + h * C1);
  float4 xa = xrp[0], xb = xrp[1];
  float xrv[8] = {xa.x, xa.y, xa.z, xa.w, xb.x, xb.y, xb.z, xb.w};
  const float4* ap = (const float4*)(att1 + h * C1);
  float4 aa = ap[0], ab = ap[1];
  float av[8] = {aa.x, aa.y, aa.z, aa.w, ab.x, ab.y, ab.z, ab.w};

  float m = -INFINITY, s = 0.f;
  float acc[8];
#pragma unroll
  for (int c = 0; c < 8; ++c) acc[c] = 0.f;

  auto gather = [&](int sn, float* v) {
    const float4* p = (const float4*)(xl1 + (size_t)sn * HC1 + h * C1);
    float4 A = p[0], B = p[1];
    v[0]=A.x; v[1]=A.y; v[2]=A.z; v[3]=A.w; v[4]=B.x; v[5]=B.y; v[6]=B.z; v[7]=B.w;
  };
  auto process = [&](const float* v) {
    float logit = 0.f;
#pragma unroll
    for (int c = 0; c < 8; ++c) {
      float u = v[c] + xrv[c];
      u = (u > 0.f) ? u : NEG * u;
      logit = fmaf(u, av[c], logit);
    }
    float mn = fmaxf(m, logit);
    float so = __expf(m - mn);
    float p  = __expf(logit - mn);
    s = s * so + p;
#pragma unroll
    for (int c = 0; c < 8; ++c) acc[c] = fmaf(acc[c], so, p * v[c]);
    m = mn;
  };

  int beg = rowptr[node], end = rowptr[node + 1];
  int i = beg;
  for (; i + 1 < end; i += 2) {
    int sn0 = esrc[i], sn1 = esrc[i + 1];
    if ((unsigned)sn0 >= N_NODES) sn0 = node;   // defensive: never OOB
    if ((unsigned)sn1 >= N_NODES) sn1 = node;
    float v0[8], v1[8];
    gather(sn0, v0); gather(sn1, v1);
    process(v0); process(v1);
  }
  if (i < end) {
    int sn0 = esrc[i];
    if ((unsigned)sn0 >= N_NODES) sn0 = node;
    float v0[8]; gather(sn0, v0); process(v0);
  }

  float inv = (s > 0.f) ? 1.f / s : 0.f;        // defensive: no 0/0 NaN
  float o[8];
#pragma unroll
  for (int c = 0; c < 8; ++c) {
    float v = fmaf(acc[c], inv, b1[h * C1 + c]);
    o[c] = (v > 0.f) ? v : expm1f(v);    // ELU
  }
  float4* hp = (float4*)(hbuf + (size_t)node * HC1 + h * C1);
  hp[0] = make_float4(o[0], o[1], o[2], o[3]);
  hp[1] = make_float4(o[4], o[5], o[6], o[7]);
}

// ---------------- GEMM2: xl2 = h@W2l, xr2 = h@W2r  (64 -> 24 each) -----------
__global__ __launch_bounds__(256) void k_gemm2(const float* __restrict__ hbuf,
    const float* __restrict__ W2l, const float* __restrict__ W2r,
    float* __restrict__ xl2, float* __restrict__ xr2) {
  __shared__ float w[64][48];
  int tid = threadIdx.x;
  for (int i = tid; i < 64 * 48; i += 256) {
    int k = i / 48, j = i - k * 48;
    w[k][j] = (j < HC2) ? W2l[k * HC2 + j] : W2r[k * HC2 + (j - HC2)];
  }
  __syncthreads();
  int node = blockIdx.x * 256 + tid;
  if (node >= N_NODES) return;
  float acc[48];
#pragma unroll
  for (int j = 0; j < 48; ++j) acc[j] = 0.f;
  const float4* hp = (const float4*)(hbuf + (size_t)node * HC1);
  for (int k0 = 0; k0 < 64; k0 += 16) {
    float rv[16];
#pragma unroll
    for (int q = 0; q < 4; ++q) {
      float4 r4 = hp[k0 / 4 + q];
      rv[q*4+0] = r4.x; rv[q*4+1] = r4.y; rv[q*4+2] = r4.z; rv[q*4+3] = r4.w;
    }
#pragma unroll
    for (int kk = 0; kk < 16; ++kk) {
      float hv = rv[kk];
      const float4* wrow = (const float4*)&w[k0 + kk][0];
#pragma unroll
      for (int j4 = 0; j4 < 12; ++j4) {
        float4 wv = wrow[j4];
        acc[j4*4+0] = fmaf(hv, wv.x, acc[j4*4+0]);
        acc[j4*4+1] = fmaf(hv, wv.y, acc[j4*4+1]);
        acc[j4*4+2] = fmaf(hv, wv.z, acc[j4*4+2]);
        acc[j4*4+3] = fmaf(hv, wv.w, acc[j4*4+3]);
      }
    }
  }
  float4* lp = (float4*)(xl2 + (size_t)node * HC2);
  float4* rp = (float4*)(xr2 + (size_t)node * HC2);
#pragma unroll
  for (int j4 = 0; j4 < 6; ++j4) {
    lp[j4] = make_float4(acc[j4*4+0], acc[j4*4+1], acc[j4*4+2], acc[j4*4+3]);
    rp[j4] = make_float4(acc[24+j4*4+0], acc[24+j4*4+1], acc[24+j4*4+2], acc[24+j4*4+3]);
  }
}

// ---------------- layer-2 edge pass + head-mean + final softmax --------------
__global__ __launch_bounds__(256) void k_edge2(const float* __restrict__ xl2,
    const float* __restrict__ xr2, const float* __restrict__ att2,
    const float* __restrict__ b2, const int* __restrict__ rowptr,
    const int* __restrict__ esrc, float* __restrict__ out) {
  int t = blockIdx.x * blockDim.x + threadIdx.x;   // exact grid: N*8
  int node = t >> 3, h = t & 7;
  float xrv[3], av[3];
#pragma unroll
  for (int c = 0; c < 3; ++c) {
    xrv[c] = xr2[(size_t)node * HC2 + h * NCLS + c];
    av[c]  = att2[h * NCLS + c];
  }
  float m = -INFINITY, s = 0.f;
  float acc[3] = {0.f, 0.f, 0.f};

  auto process = [&](const float* v) {
    float logit = 0.f;
#pragma unroll
    for (int c = 0; c < 3; ++c) {
      float u = v[c] + xrv[c];
      u = (u > 0.f) ? u : NEG * u;
      logit = fmaf(u, av[c], logit);
    }
    float mn = fmaxf(m, logit);
    float so = __expf(m - mn);
    float p  = __expf(logit - mn);
    s = s * so + p;
#pragma unroll
    for (int c = 0; c < 3; ++c) acc[c] = fmaf(acc[c], so, p * v[c]);
    m = mn;
  };

  int beg = rowptr[node], end = rowptr[node + 1];
  int i = beg;
  for (; i + 1 < end; i += 2) {
    int sn0 = esrc[i], sn1 = esrc[i + 1];
    if ((unsigned)sn0 >= N_NODES) sn0 = node;
    if ((unsigned)sn1 >= N_NODES) sn1 = node;
    float v0[3], v1[3];
#pragma unroll
    for (int c = 0; c < 3; ++c) v0[c] = xl2[(size_t)sn0 * HC2 + h * NCLS + c];
#pragma unroll
    for (int c = 0; c < 3; ++c) v1[c] = xl2[(size_t)sn1 * HC2 + h * NCLS + c];
    process(v0); process(v1);
  }
  if (i < end) {
    int sn0 = esrc[i];
    if ((unsigned)sn0 >= N_NODES) sn0 = node;
    float v0[3];
#pragma unroll
    for (int c = 0; c < 3; ++c) v0[c] = xl2[(size_t)sn0 * HC2 + h * NCLS + c];
    process(v0);
  }

  float inv = (s > 0.f) ? 1.f / s : 0.f;
  float o[3];
#pragma unroll
  for (int c = 0; c < 3; ++c) o[c] = acc[c] * inv;
  // mean over 8 heads (8-lane group butterfly; grid exact so all lanes live)
#pragma unroll
  for (int off = 1; off < 8; off <<= 1) {
#pragma unroll
    for (int c = 0; c < 3; ++c) o[c] += __shfl_xor(o[c], off);
  }
  if (h < 3) {
    float z[3];
#pragma unroll
    for (int c = 0; c < 3; ++c) z[c] = o[c] * 0.125f + b2[c];
    float mx = fmaxf(fmaxf(z[0], z[1]), z[2]);
    float e0 = __expf(z[0] - mx), e1 = __expf(z[1] - mx), e2 = __expf(z[2] - mx);
    float sum = e0 + e1 + e2;
    float num = (h == 0) ? e0 : (h == 1) ? e1 : e2;
    out[(size_t)node * NCLS + h] = num / sum;
  }
}

// ---------------- launch -----------------------------------------------------
extern "C" void kernel_launch(void* const* d_in, const int* in_sizes, int n_in,
                              void* d_out, int out_size, void* d_ws, size_t ws_size,
                              hipStream_t stream) {
  (void)in_sizes; (void)n_in; (void)out_size; (void)ws_size;
  const float* x    = (const float*)d_in[0];
  const int*   ei   = (const int*)d_in[1];
  const float* W1l  = (const float*)d_in[2];
  const float* W1r  = (const float*)d_in[3];
  const float* att1 = (const float*)d_in[4];
  const float* b1   = (const float*)d_in[5];
  const float* W2l  = (const float*)d_in[6];
  const float* W2r  = (const float*)d_in[7];
  const float* att2 = (const float*)d_in[8];
  const float* b2   = (const float*)d_in[9];
  float* out = (float*)d_out;

  char* w = (char*)d_ws;
  float* xl1  = (float*)(w);                 // 25.6 MB
  float* xr1  = (float*)(w + 25600000);      // 25.6 MB
  float* hbuf = (float*)(w + 51200000);      // 25.6 MB (W image lives here pre-edge1)
  float* xl2  = (float*)(w);                 // overlays xl1 (dead after edge1)
  float* xr2  = (float*)(w + 9600000);       // inside old xl1 region
  _Float16* Wimg = (_Float16*)(w + 51200000);          // 128 KB fp16 LDS-image
  char* ip = w + 76800000;
  int* deg    = (int*)(ip);                  // 400000 B
  int* cnt    = (int*)(ip + 400000);         // 400000 B
  int* rowptr = (int*)(ip + 800000);         // 400004 B
  int* segsum = (int*)(ip + 1200256);
  int* segoff = (int*)(ip + 1200512);
  int* flag   = (int*)(ip + 1200768);
  int* esrc   = (int*)(ip + 1201024);        // 6.8 MB  -> total ~84.8 MB

  hipMemsetAsync(deg, 0, 800000, stream);    // deg + cnt (contiguous)
  hipMemsetAsync(flag, 0, 4, stream);

  k_detect   <<<16, 256, 0, stream>>>(ei, flag);
  k_wconv    <<<256, 256, 0, stream>>>(W1l, W1r, Wimg);
  k_hist     <<<(E_TOT + 255) / 256, 256, 0, stream>>>(ei, flag, deg);
  k_seg_sum  <<<NSEG, 256, 0, stream>>>(deg, segsum);
  k_scan_small<<<1, 64, 0, stream>>>(segsum, segoff, rowptr);
  k_seg_scan <<<NSEG, 256, 0, stream>>>(deg, segoff, rowptr);
  k_scatter  <<<(E_TOT + 255) / 256, 256, 0, stream>>>(ei, flag, rowptr, cnt, esrc);
  k_gemm1    <<<NBLK, 512, 0, stream>>>(x, (const uint4*)Wimg, xl1, xr1);
  k_edge1    <<<(N_NODES * HEADS) / 256, 256, 0, stream>>>(xl1, xr1, att1, b1, rowptr, esrc, hbuf);
  k_gemm2    <<<(N_NODES + 255) / 256, 256, 0, stream>>>(hbuf, W2l, W2r, xl2, xr2);
  k_edge2    <<<(N_NODES * HEADS) / 256, 256, 0, stream>>>(xl2, xr2, att2, b2, rowptr, esrc, out);
}

// Round 12
// 299.313 us; speedup vs baseline: 1.7188x; 1.3045x over previous
//
#include <hip/hip_runtime.h>
#include <cstdint>
#include <cstddef>

#define N_NODES 100000
#define E_EDGES 1600000
#define E_TOT   1700000
#define HEADS   8
#define C1      8
#define HC1     64
#define NCLS    3
#define HC2     24
#define IN_CH   500
#define NEG     0.2f

#define TILES   6250    /* 100000 / 16 */
#define NBLK    256

#define NPB     391     /* nodes per bucket */
#define NBUCK   256     /* 256*391 = 100096 >= N */
#define CHUNK   4096    /* edges per chunk block */
#define NCHUNK  416     /* ceil(1700000/4096) */
#define SCAP    8192    /* partB LDS stage capacity (mean 6641, ~19 sigma) */

typedef __attribute__((ext_vector_type(8))) _Float16 f16x8;
typedef __attribute__((ext_vector_type(4))) _Float16 f16x4;
typedef __attribute__((ext_vector_type(4))) float f32x4;

// ---------------- edge dtype detection (int32 vs int64 edge_index) -----------
__global__ void k_detect(const int* __restrict__ ei, int* __restrict__ flag) {
  int i = blockIdx.x * blockDim.x + threadIdx.x;   // 4096 threads
  bool nz = ei[2 * i + 1] != 0;
  if (__ballot(nz)) {
    if ((threadIdx.x & 63) == 0) atomicOr(flag, 1);
  }
}

__device__ __forceinline__ int edge_at(const int* __restrict__ ei, int idx, int mode) {
  return mode ? ei[idx] : ei[2 * idx];   // int64: low word
}

// ---------------- CSR build: deterministic 3-pass counting sort --------------
// ZERO global atomics. Positions are exact (scan-computed), so esrc content is
// deterministic up to intra-group LDS-atomic interleave (same class as the
// flat scatter that passed the tripwire in R5/R7/R8/R11).

// A1: per-(chunk,bucket) counts -> cmat[chunk][bucket]
__global__ __launch_bounds__(256) void k_cntA(const int* __restrict__ ei,
    const int* __restrict__ flag, int* __restrict__ cmat) {
  __shared__ int cnt[NBUCK];
  const int tid = threadIdx.x;
  const int e0 = blockIdx.x * CHUNK;
  const int mode = *flag;
  cnt[tid] = 0;
  __syncthreads();
#pragma unroll
  for (int i = 0; i < 16; ++i) {
    int e = e0 + i * 256 + tid;
    if (e < E_TOT) {
      int d = (e < E_EDGES) ? edge_at(ei, E_EDGES + e, mode) : (e - E_EDGES);
      atomicAdd(&cnt[d / NPB], 1);
    }
  }
  __syncthreads();
  cmat[blockIdx.x * NBUCK + tid] = cnt[tid];
}

// A2: deterministic scans. Thread b: exclusive scan over chunks for bucket b
// (cmat becomes within-bucket chunk offsets); then serial scan of bucket
// totals -> bbase[0..NBUCK] (bbase[NBUCK] = E_TOT) and rowptr[N].
__global__ void k_scanA(int* __restrict__ cmat, int* __restrict__ bbase,
                        int* __restrict__ rowptr) {
  __shared__ int tot[NBUCK];
  int b = threadIdx.x;
  int run = 0;
  for (int c = 0; c < NCHUNK; ++c) {
    int v = cmat[c * NBUCK + b];
    cmat[c * NBUCK + b] = run;
    run += v;
  }
  tot[b] = run;
  __syncthreads();
  if (b == 0) {
    int acc = 0;
    for (int k = 0; k < NBUCK; ++k) { int v = tot[k]; tot[k] = acc; acc += v; }
    bbase[NBUCK] = acc;          // == E_TOT
    rowptr[N_NODES] = acc;
  }
  __syncthreads();
  bbase[b] = tot[b];
}

// A3: group chunk edges by bucket in LDS (R9-proven mechanics), flush each
// group to its exact computed position bbase[b] + cmat[chunk][b] + j.
// Per-thread sequential stores -> each 64B line written by one block.
__global__ __launch_bounds__(256) void k_grpA(const int* __restrict__ ei,
    const int* __restrict__ flag, const int* __restrict__ cmat,
    const int* __restrict__ bbase, unsigned* __restrict__ bstage) {
  __shared__ int cnt[NBUCK], ofs[NBUCK], cur[NBUCK], gbase[NBUCK];
  __shared__ unsigned buf[CHUNK];      // 16 KB
  const int tid = threadIdx.x;
  const int e0 = blockIdx.x * CHUNK;
  const int mode = *flag;
  cnt[tid] = 0;
  __syncthreads();

  unsigned pk[16]; int bk[16];
#pragma unroll
  for (int i = 0; i < 16; ++i) {
    int e = e0 + i * 256 + tid;
    bk[i] = -1;
    if (e < E_TOT) {
      int s, d;
      if (e < E_EDGES) { s = edge_at(ei, e, mode); d = edge_at(ei, E_EDGES + e, mode); }
      else             { s = e - E_EDGES; d = s; }
      int b = d / NPB;
      bk[i] = b;
      pk[i] = ((unsigned)s << 9) | (unsigned)(d - b * NPB);
      atomicAdd(&cnt[b], 1);
    }
  }
  __syncthreads();
  if (tid == 0) {                      // serial scan (proven-safe idiom)
    int run = 0;
    for (int k = 0; k < NBUCK; ++k) { ofs[k] = run; run += cnt[k]; }
  }
  __syncthreads();
  cur[tid] = ofs[tid];
  gbase[tid] = bbase[tid] + cmat[blockIdx.x * NBUCK + tid];
  __syncthreads();
#pragma unroll
  for (int i = 0; i < 16; ++i) {
    if (bk[i] >= 0) {
      int slot = atomicAdd(&cur[bk[i]], 1);
      buf[slot] = pk[i];
    }
  }
  __syncthreads();
  const int n = cnt[tid], s0 = ofs[tid], g = gbase[tid];
  for (int j = 0; j < n; ++j) {
    int gp = g + j;
    if ((unsigned)gp < (unsigned)E_TOT) bstage[gp] = buf[s0 + j];
  }
}

// Pass B (R9-numerics-proven): stage bucket in LDS, histogram local nodes,
// serial scan -> rowptr snapshot, scatter into the bucket's private window.
__global__ __launch_bounds__(256) void k_partB(const unsigned* __restrict__ bstage,
    const int* __restrict__ bbase, int* __restrict__ rowptr, int* __restrict__ esrc) {
  __shared__ unsigned edges[SCAP];     // 32 KB
  __shared__ int lhist[NPB];
  __shared__ int lptr[NPB];
  const int b = blockIdx.x;
  const int tid = threadIdx.x;
  const int base = bbase[b];
  const int n = min(bbase[b + 1] - base, SCAP);
  const int nl = min(NPB, N_NODES - b * NPB);   // 391, or 295 for last bucket

  for (int k = tid; k < NPB; k += 256) lhist[k] = 0;
  for (int i = tid; i < n; i += 256) edges[i] = bstage[base + i];
  __syncthreads();
  for (int i = tid; i < n; i += 256) atomicAdd(&lhist[(int)(edges[i] & 511u)], 1);
  __syncthreads();
  if (tid == 0) {                      // serial exclusive scan
    int run = base;
    for (int k = 0; k < nl; ++k) { int v = lhist[k]; lptr[k] = run; run += v; }
  }
  __syncthreads();
  for (int k = tid; k < nl; k += 256) rowptr[b * NPB + k] = lptr[k];
  __syncthreads();                     // rowptr snapshot BEFORE lptr mutates
  for (int i = tid; i < n; i += 256) {
    unsigned pkv = edges[i];
    int pos = atomicAdd(&lptr[(int)(pkv & 511u)], 1);
    if ((unsigned)pos < (unsigned)E_TOT) esrc[pos] = (int)(pkv >> 9);
  }
}

// ---------------- W1 pre-convert to fp16 LDS-image ---------------------------
// Image layout == desired LDS layout: [col 0..127][k 0..511] fp16, row stride
// 1024B, XOR-swizzled byte ^= (col&7)<<4, k>=500 zero-padded. 128KB.
__global__ void k_wconv(const float* __restrict__ W1l, const float* __restrict__ W1r,
                        _Float16* __restrict__ Wimg) {
  int t = blockIdx.x * 256 + threadIdx.x;   // 65536 = 128*512
  int col = t >> 9, k = t & 511;
  float v = 0.f;
  if (k < IN_CH) v = (col < HC1) ? W1l[k * HC1 + col] : W1r[k * HC1 + (col - HC1)];
  int boff = (col * 1024 + k * 2) ^ ((col & 7) << 4);
  Wimg[boff >> 1] = (_Float16)v;
}

// ---------------- GEMM1: fp16 2-product MFMA, weight-stationary in LDS -------
// RACE FIX (R10 post-mortem, kept): __syncthreads() separates the MFMA loop
// (READS A region) from the split-K partial publish (WRITES A region).
#define ABASE 131072
#define ALO   16384

__global__ __launch_bounds__(512, 1) void k_gemm1(const float* __restrict__ x,
    const uint4* __restrict__ Wimg, float* __restrict__ xl, float* __restrict__ xr) {
  __shared__ char lds[163840];
  const int tid  = threadIdx.x;
  const int lane = tid & 63, wid = tid >> 6;
  const int lrow = lane & 15, kg = lane >> 4;
  const int colgrp = wid & 3;
  const int kw0 = (wid >> 2) * 8;

  // ---- copy W image (L2/L3-hot) into LDS, linear
#pragma unroll
  for (int i = 0; i < 16; ++i) {
    int idx = i * 512 + tid;
    uint4 v = Wimg[idx];
    *(uint4*)(lds + idx * 16) = v;
  }

  // ---- per-thread staging map (constant across tiles)
  int xoff[4], aoff[4], mode[4];
#pragma unroll
  for (int i = 0; i < 4; ++i) {
    int s = tid + i * 512;
    if (s < 2000) {
      int row = s / 125, c4 = s - row * 125;
      xoff[i] = row * 500 + c4 * 4;
      aoff[i] = (row * 1024 + c4 * 8) ^ ((row & 7) << 4);
      mode[i] = 0;
    } else {
      int p = s - 2000;           // 0..47
      int row = p / 3, j = p - row * 3;
      aoff[i] = (row * 1024 + 1000 + j * 8) ^ ((row & 7) << 4);
      xoff[i] = 0;
      mode[i] = 1;
    }
  }

  float4 rv[4];
  auto loadregs = [&](int tile) {
#pragma unroll
    for (int i = 0; i < 4; ++i)
      if (mode[i] == 0)
        rv[i] = *(const float4*)&x[(size_t)tile * 8000 + xoff[i]];
  };

  loadregs(blockIdx.x);
  __syncthreads();   // W table resident

  for (int tile = blockIdx.x; tile < TILES; tile += NBLK) {
    // ---- stage A: convert fp32 regs -> fp16 hi + (lo * 2048), swizzled LDS
#pragma unroll
    for (int i = 0; i < 4; ++i) {
      f16x4 h, l;
      if (mode[i] == 0) {
        float vals[4] = {rv[i].x, rv[i].y, rv[i].z, rv[i].w};
#pragma unroll
        for (int c = 0; c < 4; ++c) {
          _Float16 hh = (_Float16)vals[c];
          float r = vals[c] - (float)hh;
          h[c] = hh;
          l[c] = (_Float16)(r * 2048.f);
        }
      } else {
        h = (f16x4){0, 0, 0, 0}; l = (f16x4){0, 0, 0, 0};
      }
      *(f16x4*)(lds + ABASE + aoff[i]) = h;
      *(f16x4*)(lds + ABASE + ALO + aoff[i]) = l;
    }
    __syncthreads();   // A(t) visible
    if (tile + NBLK < TILES) loadregs(tile + NBLK);   // prefetch under compute

    // ---- compute: 8 K-windows x {2 A-frags, 2 B-frags, 4 MFMA}
    f32x4 acch[2], accl[2];
    acch[0] = (f32x4){0,0,0,0}; acch[1] = (f32x4){0,0,0,0};
    accl[0] = (f32x4){0,0,0,0}; accl[1] = (f32x4){0,0,0,0};
#pragma unroll
    for (int kw = 0; kw < 8; ++kw) {
      const int kwin = kw0 + kw;
      const int koff = kwin * 64 + kg * 16;
      int ao = (lrow * 1024 + koff) ^ ((lrow & 7) << 4);
      f16x8 ah = *(const f16x8*)(lds + ABASE + ao);
      f16x8 al = *(const f16x8*)(lds + ABASE + ALO + ao);
#pragma unroll
      for (int n = 0; n < 2; ++n) {
        int col = colgrp * 32 + n * 16 + lrow;
        int bo = (col * 1024 + koff) ^ ((col & 7) << 4);
        f16x8 b = *(const f16x8*)(lds + bo);
        acch[n] = __builtin_amdgcn_mfma_f32_16x16x32_f16(ah, b, acch[n], 0, 0, 0);
        accl[n] = __builtin_amdgcn_mfma_f32_16x16x32_f16(al, b, accl[n], 0, 0, 0);
      }
    }
    // ---- epilogue: v = acc_h + acc_l/2048; split-K combine via LDS
    float v[2][4];
#pragma unroll
    for (int n = 0; n < 2; ++n)
#pragma unroll
      for (int j = 0; j < 4; ++j)
        v[n][j] = acch[n][j] + accl[n][j] * 4.8828125e-4f;

    __syncthreads();  // RACE FIX: all waves done READING A region before reuse

    if (wid >= 4) {   // upper K-half: publish partials into A region (dead now)
      char* p = lds + ABASE + ((wid - 4) * 64 + lane) * 32;
      *(float4*)p       = make_float4(v[0][0], v[0][1], v[0][2], v[0][3]);
      *(float4*)(p+16)  = make_float4(v[1][0], v[1][1], v[1][2], v[1][3]);
    }
    __syncthreads();
    if (wid < 4) {    // lower K-half: combine + store C
      const char* p = lds + ABASE + (wid * 64 + lane) * 32;
      float4 p0 = *(const float4*)p, p1 = *(const float4*)(p+16);
      v[0][0]+=p0.x; v[0][1]+=p0.y; v[0][2]+=p0.z; v[0][3]+=p0.w;
      v[1][0]+=p1.x; v[1][1]+=p1.y; v[1][2]+=p1.z; v[1][3]+=p1.w;
      float* dst = (colgrp < 2) ? xl : xr;
      const int bm0 = tile * 16;
#pragma unroll
      for (int n = 0; n < 2; ++n) {
        int cc = (colgrp * 32 + n * 16 + lrow) & 63;
#pragma unroll
        for (int j = 0; j < 4; ++j)
          dst[(size_t)(bm0 + kg * 4 + j) * HC1 + cc] = v[n][j];
      }
    }
    __syncthreads();  // partials consumed; A region free for next stage
  }
}

// ---------------- layer-1 edge pass: online segment softmax + aggregate ------
// thread = (node, head); 8 consecutive lanes = 8 heads of one node.
// 2-way edge unroll (R5-proven; 4-way regressed in R8).
__global__ __launch_bounds__(256) void k_edge1(const float* __restrict__ xl1,
    const float* __restrict__ xr1, const float* __restrict__ att1,
    const float* __restrict__ b1, const int* __restrict__ rowptr,
    const int* __restrict__ esrc, float* __restrict__ hbuf) {
  int t = blockIdx.x * blockDim.x + threadIdx.x;   // exact grid: N*8
  int node = t >> 3, h = t & 7;
  const float4* xrp = (const float4*)(xr1 + (size_t)node * HC1 + h * C1);
  float4 xa = xrp[0], xb = xrp[1];
  float xrv[8] = {xa.x, xa.y, xa.z, xa.w, xb.x, xb.y, xb.z, xb.w};
  const float4* ap = (const float4*)(att1 + h * C1);
  float4 aa = ap[0], ab = ap[1];
  float av[8] = {aa.x, aa.y, aa.z, aa.w, ab.x, ab.y, ab.z, ab.w};

  float m = -INFINITY, s = 0.f;
  float acc[8];
#pragma unroll
  for (int c = 0; c < 8; ++c) acc[c] = 0.f;

  auto gather = [&](int sn, float* v) {
    const float4* p = (const float4*)(xl1 + (size_t)sn * HC1 + h * C1);
    float4 A = p[0], B = p[1];
    v[0]=A.x; v[1]=A.y; v[2]=A.z; v[3]=A.w; v[4]=B.x; v[5]=B.y; v[6]=B.z; v[7]=B.w;
  };
  auto process = [&](const float* v) {
    float logit = 0.f;
#pragma unroll
    for (int c = 0; c < 8; ++c) {
      float u = v[c] + xrv[c];
      u = (u > 0.f) ? u : NEG * u;
      logit = fmaf(u, av[c], logit);
    }
    float mn = fmaxf(m, logit);
    float so = __expf(m - mn);
    float p  = __expf(logit - mn);
    s = s * so + p;
#pragma unroll
    for (int c = 0; c < 8; ++c) acc[c] = fmaf(acc[c], so, p * v[c]);
    m = mn;
  };

  int beg = rowptr[node], end = rowptr[node + 1];
  int i = beg;
  for (; i + 1 < end; i += 2) {
    int sn0 = esrc[i], sn1 = esrc[i + 1];
    if ((unsigned)sn0 >= N_NODES) sn0 = node;   // defensive: never OOB
    if ((unsigned)sn1 >= N_NODES) sn1 = node;
    float v0[8], v1[8];
    gather(sn0, v0); gather(sn1, v1);
    process(v0); process(v1);
  }
  if (i < end) {
    int sn0 = esrc[i];
    if ((unsigned)sn0 >= N_NODES) sn0 = node;
    float v0[8]; gather(sn0, v0); process(v0);
  }

  float inv = (s > 0.f) ? 1.f / s : 0.f;        // defensive: no 0/0 NaN
  float o[8];
#pragma unroll
  for (int c = 0; c < 8; ++c) {
    float v = fmaf(acc[c], inv, b1[h * C1 + c]);
    o[c] = (v > 0.f) ? v : expm1f(v);    // ELU
  }
  float4* hp = (float4*)(hbuf + (size_t)node * HC1 + h * C1);
  hp[0] = make_float4(o[0], o[1], o[2], o[3]);
  hp[1] = make_float4(o[4], o[5], o[6], o[7]);
}

// ---------------- GEMM2: xl2 = h@W2l, xr2 = h@W2r  (64 -> 24 each) -----------
__global__ __launch_bounds__(256) void k_gemm2(const float* __restrict__ hbuf,
    const float* __restrict__ W2l, const float* __restrict__ W2r,
    float* __restrict__ xl2, float* __restrict__ xr2) {
  __shared__ float w[64][48];
  int tid = threadIdx.x;
  for (int i = tid; i < 64 * 48; i += 256) {
    int k = i / 48, j = i - k * 48;
    w[k][j] = (j < HC2) ? W2l[k * HC2 + j] : W2r[k * HC2 + (j - HC2)];
  }
  __syncthreads();
  int node = blockIdx.x * 256 + tid;
  if (node >= N_NODES) return;
  float acc[48];
#pragma unroll
  for (int j = 0; j < 48; ++j) acc[j] = 0.f;
  const float4* hp = (const float4*)(hbuf + (size_t)node * HC1);
  for (int k0 = 0; k0 < 64; k0 += 16) {
    float rv[16];
#pragma unroll
    for (int q = 0; q < 4; ++q) {
      float4 r4 = hp[k0 / 4 + q];
      rv[q*4+0] = r4.x; rv[q*4+1] = r4.y; rv[q*4+2] = r4.z; rv[q*4+3] = r4.w;
    }
#pragma unroll
    for (int kk = 0; kk < 16; ++kk) {
      float hv = rv[kk];
      const float4* wrow = (const float4*)&w[k0 + kk][0];
#pragma unroll
      for (int j4 = 0; j4 < 12; ++j4) {
        float4 wv = wrow[j4];
        acc[j4*4+0] = fmaf(hv, wv.x, acc[j4*4+0]);
        acc[j4*4+1] = fmaf(hv, wv.y, acc[j4*4+1]);
        acc[j4*4+2] = fmaf(hv, wv.z, acc[j4*4+2]);
        acc[j4*4+3] = fmaf(hv, wv.w, acc[j4*4+3]);
      }
    }
  }
  float4* lp = (float4*)(xl2 + (size_t)node * HC2);
  float4* rp = (float4*)(xr2 + (size_t)node * HC2);
#pragma unroll
  for (int j4 = 0; j4 < 6; ++j4) {
    lp[j4] = make_float4(acc[j4*4+0], acc[j4*4+1], acc[j4*4+2], acc[j4*4+3]);
    rp[j4] = make_float4(acc[24+j4*4+0], acc[24+j4*4+1], acc[24+j4*4+2], acc[24+j4*4+3]);
  }
}

// ---------------- layer-2 edge pass + head-mean + final softmax --------------
__global__ __launch_bounds__(256) void k_edge2(const float* __restrict__ xl2,
    const float* __restrict__ xr2, const float* __restrict__ att2,
    const float* __restrict__ b2, const int* __restrict__ rowptr,
    const int* __restrict__ esrc, float* __restrict__ out) {
  int t = blockIdx.x * blockDim.x + threadIdx.x;   // exact grid: N*8
  int node = t >> 3, h = t & 7;
  float xrv[3], av[3];
#pragma unroll
  for (int c = 0; c < 3; ++c) {
    xrv[c] = xr2[(size_t)node * HC2 + h * NCLS + c];
    av[c]  = att2[h * NCLS + c];
  }
  float m = -INFINITY, s = 0.f;
  float acc[3] = {0.f, 0.f, 0.f};

  auto process = [&](const float* v) {
    float logit = 0.f;
#pragma unroll
    for (int c = 0; c < 3; ++c) {
      float u = v[c] + xrv[c];
      u = (u > 0.f) ? u : NEG * u;
      logit = fmaf(u, av[c], logit);
    }
    float mn = fmaxf(m, logit);
    float so = __expf(m - mn);
    float p  = __expf(logit - mn);
    s = s * so + p;
#pragma unroll
    for (int c = 0; c < 3; ++c) acc[c] = fmaf(acc[c], so, p * v[c]);
    m = mn;
  };

  int beg = rowptr[node], end = rowptr[node + 1];
  int i = beg;
  for (; i + 1 < end; i += 2) {
    int sn0 = esrc[i], sn1 = esrc[i + 1];
    if ((unsigned)sn0 >= N_NODES) sn0 = node;
    if ((unsigned)sn1 >= N_NODES) sn1 = node;
    float v0[3], v1[3];
#pragma unroll
    for (int c = 0; c < 3; ++c) v0[c] = xl2[(size_t)sn0 * HC2 + h * NCLS + c];
#pragma unroll
    for (int c = 0; c < 3; ++c) v1[c] = xl2[(size_t)sn1 * HC2 + h * NCLS + c];
    process(v0); process(v1);
  }
  if (i < end) {
    int sn0 = esrc[i];
    if ((unsigned)sn0 >= N_NODES) sn0 = node;
    float v0[3];
#pragma unroll
    for (int c = 0; c < 3; ++c) v0[c] = xl2[(size_t)sn0 * HC2 + h * NCLS + c];
    process(v0);
  }

  float inv = (s > 0.f) ? 1.f / s : 0.f;
  float o[3];
#pragma unroll
  for (int c = 0; c < 3; ++c) o[c] = acc[c] * inv;
  // mean over 8 heads (8-lane group butterfly; grid exact so all lanes live)
#pragma unroll
  for (int off = 1; off < 8; off <<= 1) {
#pragma unroll
    for (int c = 0; c < 3; ++c) o[c] += __shfl_xor(o[c], off);
  }
  if (h < 3) {
    float z[3];
#pragma unroll
    for (int c = 0; c < 3; ++c) z[c] = o[c] * 0.125f + b2[c];
    float mx = fmaxf(fmaxf(z[0], z[1]), z[2]);
    float e0 = __expf(z[0] - mx), e1 = __expf(z[1] - mx), e2 = __expf(z[2] - mx);
    float sum = e0 + e1 + e2;
    float num = (h == 0) ? e0 : (h == 1) ? e1 : e2;
    out[(size_t)node * NCLS + h] = num / sum;
  }
}

// ---------------- launch -----------------------------------------------------
extern "C" void kernel_launch(void* const* d_in, const int* in_sizes, int n_in,
                              void* d_out, int out_size, void* d_ws, size_t ws_size,
                              hipStream_t stream) {
  (void)in_sizes; (void)n_in; (void)out_size; (void)ws_size;
  const float* x    = (const float*)d_in[0];
  const int*   ei   = (const int*)d_in[1];
  const float* W1l  = (const float*)d_in[2];
  const float* W1r  = (const float*)d_in[3];
  const float* att1 = (const float*)d_in[4];
  const float* b1   = (const float*)d_in[5];
  const float* W2l  = (const float*)d_in[6];
  const float* W2r  = (const float*)d_in[7];
  const float* att2 = (const float*)d_in[8];
  const float* b2   = (const float*)d_in[9];
  float* out = (float*)d_out;

  char* w = (char*)d_ws;
  float* xl1  = (float*)(w);                 // 25.6 MB (bstage overlays pre-gemm1)
  float* xr1  = (float*)(w + 25600000);      // 25.6 MB
  float* hbuf = (float*)(w + 51200000);      // 25.6 MB (W image lives here pre-edge1)
  float* xl2  = (float*)(w);                 // overlays xl1 (dead after edge1)
  float* xr2  = (float*)(w + 9600000);       // inside old xl1 region
  _Float16* Wimg = (_Float16*)(w + 51200000);          // 128 KB fp16 LDS-image
  unsigned* bstage = (unsigned*)(w);         // 6.8 MB, dead before gemm1 writes xl1
  char* ip = w + 76800000;
  int* rowptr = (int*)(ip);                  // 400,004 B
  int* cmat   = (int*)(ip + 400128);         // 416*256*4 = 425,984 B
  int* bbase  = (int*)(ip + 826112);         // 257*4 = 1,028 B
  int* flag   = (int*)(ip + 827392);         // 4 B
  int* esrc   = (int*)(ip + 827648);         // 6.8 MB -> total ~84.4 MB (ws = 800 MB)

  hipMemsetAsync(flag, 0, 4, stream);

  k_detect <<<16, 256, 0, stream>>>(ei, flag);
  k_wconv  <<<256, 256, 0, stream>>>(W1l, W1r, Wimg);
  k_cntA   <<<NCHUNK, 256, 0, stream>>>(ei, flag, cmat);
  k_scanA  <<<1, NBUCK, 0, stream>>>(cmat, bbase, rowptr);
  k_grpA   <<<NCHUNK, 256, 0, stream>>>(ei, flag, cmat, bbase, bstage);
  k_partB  <<<NBUCK, 256, 0, stream>>>(bstage, bbase, rowptr, esrc);
  k_gemm1  <<<NBLK, 512, 0, stream>>>(x, (const uint4*)Wimg, xl1, xr1);
  k_edge1  <<<(N_NODES * HEADS) / 256, 256, 0, stream>>>(xl1, xr1, att1, b1, rowptr, esrc, hbuf);
  k_gemm2  <<<(N_NODES + 255) / 256, 256, 0, stream>>>(hbuf, W2l, W2r, xl2, xr2);
  k_edge2  <<<(N_NODES * HEADS) / 256, 256, 0, stream>>>(xl2, xr2, att2, b2, rowptr, esrc, out);
}

// Round 13
// 258.848 us; speedup vs baseline: 1.9874x; 1.1563x over previous
//
#include <hip/hip_runtime.h>
#include <cstdint>
#include <cstddef>

#define N_NODES 100000
#define E_EDGES 1600000
#define E_TOT   1700000
#define HEADS   8
#define C1      8
#define HC1     64
#define NCLS    3
#define HC2     24
#define IN_CH   500
#define NEG     0.2f

#define TILES   6250    /* 100000 / 16 */
#define NBLK    256

#define NPB     391     /* nodes per bucket */
#define NBUCK   256     /* 256*391 = 100096 >= N */
#define CHUNK   4096    /* edges per chunk block */
#define NCHUNK  416     /* ceil(1700000/4096) */
#define SCAP    8192    /* partB LDS stage capacity (mean 6641, ~19 sigma) */

typedef __attribute__((ext_vector_type(8))) _Float16 f16x8;
typedef __attribute__((ext_vector_type(4))) _Float16 f16x4;
typedef __attribute__((ext_vector_type(4))) float f32x4;

// ---------------- edge dtype detection (int32 vs int64 edge_index) -----------
__global__ void k_detect(const int* __restrict__ ei, int* __restrict__ flag) {
  int i = blockIdx.x * blockDim.x + threadIdx.x;   // 4096 threads
  bool nz = ei[2 * i + 1] != 0;
  if (__ballot(nz)) {
    if ((threadIdx.x & 63) == 0) atomicOr(flag, 1);
  }
}

__device__ __forceinline__ int edge_at(const int* __restrict__ ei, int idx, int mode) {
  return mode ? ei[idx] : ei[2 * idx];   // int64: low word
}

// ---------------- CSR build: deterministic 3-pass counting sort (R12-proven) -
// ZERO global atomics; positions exact -> tripwire-stable.

__global__ __launch_bounds__(256) void k_cntA(const int* __restrict__ ei,
    const int* __restrict__ flag, int* __restrict__ cmat) {
  __shared__ int cnt[NBUCK];
  const int tid = threadIdx.x;
  const int e0 = blockIdx.x * CHUNK;
  const int mode = *flag;
  cnt[tid] = 0;
  __syncthreads();
#pragma unroll
  for (int i = 0; i < 16; ++i) {
    int e = e0 + i * 256 + tid;
    if (e < E_TOT) {
      int d = (e < E_EDGES) ? edge_at(ei, E_EDGES + e, mode) : (e - E_EDGES);
      atomicAdd(&cnt[d / NPB], 1);
    }
  }
  __syncthreads();
  cmat[blockIdx.x * NBUCK + tid] = cnt[tid];
}

__global__ void k_scanA(int* __restrict__ cmat, int* __restrict__ bbase,
                        int* __restrict__ rowptr) {
  __shared__ int tot[NBUCK];
  int b = threadIdx.x;
  int run = 0;
  for (int c = 0; c < NCHUNK; ++c) {
    int v = cmat[c * NBUCK + b];
    cmat[c * NBUCK + b] = run;
    run += v;
  }
  tot[b] = run;
  __syncthreads();
  if (b == 0) {
    int acc = 0;
    for (int k = 0; k < NBUCK; ++k) { int v = tot[k]; tot[k] = acc; acc += v; }
    bbase[NBUCK] = acc;          // == E_TOT
    rowptr[N_NODES] = acc;
  }
  __syncthreads();
  bbase[b] = tot[b];
}

__global__ __launch_bounds__(256) void k_grpA(const int* __restrict__ ei,
    const int* __restrict__ flag, const int* __restrict__ cmat,
    const int* __restrict__ bbase, unsigned* __restrict__ bstage) {
  __shared__ int cnt[NBUCK], ofs[NBUCK], cur[NBUCK], gbase[NBUCK];
  __shared__ unsigned buf[CHUNK];      // 16 KB
  const int tid = threadIdx.x;
  const int e0 = blockIdx.x * CHUNK;
  const int mode = *flag;
  cnt[tid] = 0;
  __syncthreads();

  unsigned pk[16]; int bk[16];
#pragma unroll
  for (int i = 0; i < 16; ++i) {
    int e = e0 + i * 256 + tid;
    bk[i] = -1;
    if (e < E_TOT) {
      int s, d;
      if (e < E_EDGES) { s = edge_at(ei, e, mode); d = edge_at(ei, E_EDGES + e, mode); }
      else             { s = e - E_EDGES; d = s; }
      int b = d / NPB;
      bk[i] = b;
      pk[i] = ((unsigned)s << 9) | (unsigned)(d - b * NPB);
      atomicAdd(&cnt[b], 1);
    }
  }
  __syncthreads();
  if (tid == 0) {
    int run = 0;
    for (int k = 0; k < NBUCK; ++k) { ofs[k] = run; run += cnt[k]; }
  }
  __syncthreads();
  cur[tid] = ofs[tid];
  gbase[tid] = bbase[tid] + cmat[blockIdx.x * NBUCK + tid];
  __syncthreads();
#pragma unroll
  for (int i = 0; i < 16; ++i) {
    if (bk[i] >= 0) {
      int slot = atomicAdd(&cur[bk[i]], 1);
      buf[slot] = pk[i];
    }
  }
  __syncthreads();
  const int n = cnt[tid], s0 = ofs[tid], g = gbase[tid];
  for (int j = 0; j < n; ++j) {
    int gp = g + j;
    if ((unsigned)gp < (unsigned)E_TOT) bstage[gp] = buf[s0 + j];
  }
}

__global__ __launch_bounds__(256) void k_partB(const unsigned* __restrict__ bstage,
    const int* __restrict__ bbase, int* __restrict__ rowptr, int* __restrict__ esrc) {
  __shared__ unsigned edges[SCAP];     // 32 KB
  __shared__ int lhist[NPB];
  __shared__ int lptr[NPB];
  const int b = blockIdx.x;
  const int tid = threadIdx.x;
  const int base = bbase[b];
  const int n = min(bbase[b + 1] - base, SCAP);
  const int nl = min(NPB, N_NODES - b * NPB);   // 391, or 295 for last bucket

  for (int k = tid; k < NPB; k += 256) lhist[k] = 0;
  for (int i = tid; i < n; i += 256) edges[i] = bstage[base + i];
  __syncthreads();
  for (int i = tid; i < n; i += 256) atomicAdd(&lhist[(int)(edges[i] & 511u)], 1);
  __syncthreads();
  if (tid == 0) {
    int run = base;
    for (int k = 0; k < nl; ++k) { int v = lhist[k]; lptr[k] = run; run += v; }
  }
  __syncthreads();
  for (int k = tid; k < nl; k += 256) rowptr[b * NPB + k] = lptr[k];
  __syncthreads();                     // rowptr snapshot BEFORE lptr mutates
  for (int i = tid; i < n; i += 256) {
    unsigned pkv = edges[i];
    int pos = atomicAdd(&lptr[(int)(pkv & 511u)], 1);
    if ((unsigned)pos < (unsigned)E_TOT) esrc[pos] = (int)(pkv >> 9);
  }
}

// ---------------- W1 pre-convert to fp16 LDS-image ---------------------------
__global__ void k_wconv(const float* __restrict__ W1l, const float* __restrict__ W1r,
                        _Float16* __restrict__ Wimg) {
  int t = blockIdx.x * 256 + threadIdx.x;   // 65536 = 128*512
  int col = t >> 9, k = t & 511;
  float v = 0.f;
  if (k < IN_CH) v = (col < HC1) ? W1l[k * HC1 + col] : W1r[k * HC1 + (col - HC1)];
  int boff = (col * 1024 + k * 2) ^ ((col & 7) << 4);
  Wimg[boff >> 1] = (_Float16)v;
}

// ---------------- GEMM1: fp16 2-product MFMA, weight-stationary in LDS -------
// xl written as fp16 (edge1 gathers it -> halves gather bytes); xr stays fp32.
#define ABASE 131072
#define ALO   16384

__global__ __launch_bounds__(512, 1) void k_gemm1(const float* __restrict__ x,
    const uint4* __restrict__ Wimg, _Float16* __restrict__ xlh,
    float* __restrict__ xr) {
  __shared__ char lds[163840];
  const int tid  = threadIdx.x;
  const int lane = tid & 63, wid = tid >> 6;
  const int lrow = lane & 15, kg = lane >> 4;
  const int colgrp = wid & 3;
  const int kw0 = (wid >> 2) * 8;

#pragma unroll
  for (int i = 0; i < 16; ++i) {
    int idx = i * 512 + tid;
    uint4 v = Wimg[idx];
    *(uint4*)(lds + idx * 16) = v;
  }

  int xoff[4], aoff[4], mode[4];
#pragma unroll
  for (int i = 0; i < 4; ++i) {
    int s = tid + i * 512;
    if (s < 2000) {
      int row = s / 125, c4 = s - row * 125;
      xoff[i] = row * 500 + c4 * 4;
      aoff[i] = (row * 1024 + c4 * 8) ^ ((row & 7) << 4);
      mode[i] = 0;
    } else {
      int p = s - 2000;           // 0..47
      int row = p / 3, j = p - row * 3;
      aoff[i] = (row * 1024 + 1000 + j * 8) ^ ((row & 7) << 4);
      xoff[i] = 0;
      mode[i] = 1;
    }
  }

  float4 rv[4];
  auto loadregs = [&](int tile) {
#pragma unroll
    for (int i = 0; i < 4; ++i)
      if (mode[i] == 0)
        rv[i] = *(const float4*)&x[(size_t)tile * 8000 + xoff[i]];
  };

  loadregs(blockIdx.x);
  __syncthreads();   // W table resident

  for (int tile = blockIdx.x; tile < TILES; tile += NBLK) {
#pragma unroll
    for (int i = 0; i < 4; ++i) {
      f16x4 h, l;
      if (mode[i] == 0) {
        float vals[4] = {rv[i].x, rv[i].y, rv[i].z, rv[i].w};
#pragma unroll
        for (int c = 0; c < 4; ++c) {
          _Float16 hh = (_Float16)vals[c];
          float r = vals[c] - (float)hh;
          h[c] = hh;
          l[c] = (_Float16)(r * 2048.f);
        }
      } else {
        h = (f16x4){0, 0, 0, 0}; l = (f16x4){0, 0, 0, 0};
      }
      *(f16x4*)(lds + ABASE + aoff[i]) = h;
      *(f16x4*)(lds + ABASE + ALO + aoff[i]) = l;
    }
    __syncthreads();   // A(t) visible
    if (tile + NBLK < TILES) loadregs(tile + NBLK);   // prefetch under compute

    f32x4 acch[2], accl[2];
    acch[0] = (f32x4){0,0,0,0}; acch[1] = (f32x4){0,0,0,0};
    accl[0] = (f32x4){0,0,0,0}; accl[1] = (f32x4){0,0,0,0};
#pragma unroll
    for (int kw = 0; kw < 8; ++kw) {
      const int kwin = kw0 + kw;
      const int koff = kwin * 64 + kg * 16;
      int ao = (lrow * 1024 + koff) ^ ((lrow & 7) << 4);
      f16x8 ah = *(const f16x8*)(lds + ABASE + ao);
      f16x8 al = *(const f16x8*)(lds + ABASE + ALO + ao);
#pragma unroll
      for (int n = 0; n < 2; ++n) {
        int col = colgrp * 32 + n * 16 + lrow;
        int bo = (col * 1024 + koff) ^ ((col & 7) << 4);
        f16x8 b = *(const f16x8*)(lds + bo);
        acch[n] = __builtin_amdgcn_mfma_f32_16x16x32_f16(ah, b, acch[n], 0, 0, 0);
        accl[n] = __builtin_amdgcn_mfma_f32_16x16x32_f16(al, b, accl[n], 0, 0, 0);
      }
    }
    float v[2][4];
#pragma unroll
    for (int n = 0; n < 2; ++n)
#pragma unroll
      for (int j = 0; j < 4; ++j)
        v[n][j] = acch[n][j] + accl[n][j] * 4.8828125e-4f;

    __syncthreads();  // RACE FIX (R10): all waves done READING A before reuse

    if (wid >= 4) {   // upper K-half: publish partials into A region (dead now)
      char* p = lds + ABASE + ((wid - 4) * 64 + lane) * 32;
      *(float4*)p       = make_float4(v[0][0], v[0][1], v[0][2], v[0][3]);
      *(float4*)(p+16)  = make_float4(v[1][0], v[1][1], v[1][2], v[1][3]);
    }
    __syncthreads();
    if (wid < 4) {    // lower K-half: combine + store C
      const char* p = lds + ABASE + (wid * 64 + lane) * 32;
      float4 p0 = *(const float4*)p, p1 = *(const float4*)(p+16);
      v[0][0]+=p0.x; v[0][1]+=p0.y; v[0][2]+=p0.z; v[0][3]+=p0.w;
      v[1][0]+=p1.x; v[1][1]+=p1.y; v[1][2]+=p1.z; v[1][3]+=p1.w;
      const int bm0 = tile * 16;
      if (colgrp < 2) {         // xl -> fp16
#pragma unroll
        for (int n = 0; n < 2; ++n) {
          int cc = colgrp * 32 + n * 16 + lrow;
#pragma unroll
          for (int j = 0; j < 4; ++j)
            xlh[(size_t)(bm0 + kg * 4 + j) * HC1 + cc] = (_Float16)v[n][j];
        }
      } else {                  // xr -> fp32
#pragma unroll
        for (int n = 0; n < 2; ++n) {
          int cc = (colgrp - 2) * 32 + n * 16 + lrow;
#pragma unroll
          for (int j = 0; j < 4; ++j)
            xr[(size_t)(bm0 + kg * 4 + j) * HC1 + cc] = v[n][j];
        }
      }
    }
    __syncthreads();  // partials consumed; A region free for next stage
  }
}

// ---------------- layer-1 edge pass: fp16 xl gathers -------------------------
__global__ __launch_bounds__(256) void k_edge1(const _Float16* __restrict__ xl1h,
    const float* __restrict__ xr1, const float* __restrict__ att1,
    const float* __restrict__ b1, const int* __restrict__ rowptr,
    const int* __restrict__ esrc, float* __restrict__ hbuf) {
  int t = blockIdx.x * blockDim.x + threadIdx.x;   // exact grid: N*8
  int node = t >> 3, h = t & 7;
  const float4* xrp = (const float4*)(xr1 + (size_t)node * HC1 + h * C1);
  float4 xa = xrp[0], xb = xrp[1];
  float xrv[8] = {xa.x, xa.y, xa.z, xa.w, xb.x, xb.y, xb.z, xb.w};
  const float4* ap = (const float4*)(att1 + h * C1);
  float4 aa = ap[0], ab = ap[1];
  float av[8] = {aa.x, aa.y, aa.z, aa.w, ab.x, ab.y, ab.z, ab.w};

  float m = -INFINITY, s = 0.f;
  float acc[8];
#pragma unroll
  for (int c = 0; c < 8; ++c) acc[c] = 0.f;

  auto gather = [&](int sn, float* v) {
    f16x8 q = *(const f16x8*)(xl1h + (size_t)sn * HC1 + h * C1);  // 16B
#pragma unroll
    for (int c = 0; c < 8; ++c) v[c] = (float)q[c];
  };
  auto process = [&](const float* v) {
    float logit = 0.f;
#pragma unroll
    for (int c = 0; c < 8; ++c) {
      float u = v[c] + xrv[c];
      u = (u > 0.f) ? u : NEG * u;
      logit = fmaf(u, av[c], logit);
    }
    float mn = fmaxf(m, logit);
    float so = __expf(m - mn);
    float p  = __expf(logit - mn);
    s = s * so + p;
#pragma unroll
    for (int c = 0; c < 8; ++c) acc[c] = fmaf(acc[c], so, p * v[c]);
    m = mn;
  };

  int beg = rowptr[node], end = rowptr[node + 1];
  int i = beg;
  for (; i + 1 < end; i += 2) {
    int sn0 = esrc[i], sn1 = esrc[i + 1];
    if ((unsigned)sn0 >= N_NODES) sn0 = node;   // defensive: never OOB
    if ((unsigned)sn1 >= N_NODES) sn1 = node;
    float v0[8], v1[8];
    gather(sn0, v0); gather(sn1, v1);
    process(v0); process(v1);
  }
  if (i < end) {
    int sn0 = esrc[i];
    if ((unsigned)sn0 >= N_NODES) sn0 = node;
    float v0[8]; gather(sn0, v0); process(v0);
  }

  float inv = (s > 0.f) ? 1.f / s : 0.f;        // defensive: no 0/0 NaN
  float o[8];
#pragma unroll
  for (int c = 0; c < 8; ++c) {
    float v = fmaf(acc[c], inv, b1[h * C1 + c]);
    o[c] = (v > 0.f) ? v : expm1f(v);    // ELU
  }
  float4* hp = (float4*)(hbuf + (size_t)node * HC1 + h * C1);
  hp[0] = make_float4(o[0], o[1], o[2], o[3]);
  hp[1] = make_float4(o[4], o[5], o[6], o[7]);
}

// ---------------- GEMM2: xl2 -> padded fp16 [node][h*4+c]; xr2 fp32 ----------
__global__ __launch_bounds__(256) void k_gemm2(const float* __restrict__ hbuf,
    const float* __restrict__ W2l, const float* __restrict__ W2r,
    _Float16* __restrict__ xl2p, float* __restrict__ xr2) {
  __shared__ float w[64][48];
  int tid = threadIdx.x;
  for (int i = tid; i < 64 * 48; i += 256) {
    int k = i / 48, j = i - k * 48;
    w[k][j] = (j < HC2) ? W2l[k * HC2 + j] : W2r[k * HC2 + (j - HC2)];
  }
  __syncthreads();
  int node = blockIdx.x * 256 + tid;
  if (node >= N_NODES) return;
  float acc[48];
#pragma unroll
  for (int j = 0; j < 48; ++j) acc[j] = 0.f;
  const float4* hp = (const float4*)(hbuf + (size_t)node * HC1);
  for (int k0 = 0; k0 < 64; k0 += 16) {
    float rv[16];
#pragma unroll
    for (int q = 0; q < 4; ++q) {
      float4 r4 = hp[k0 / 4 + q];
      rv[q*4+0] = r4.x; rv[q*4+1] = r4.y; rv[q*4+2] = r4.z; rv[q*4+3] = r4.w;
    }
#pragma unroll
    for (int kk = 0; kk < 16; ++kk) {
      float hv = rv[kk];
      const float4* wrow = (const float4*)&w[k0 + kk][0];
#pragma unroll
      for (int j4 = 0; j4 < 12; ++j4) {
        float4 wv = wrow[j4];
        acc[j4*4+0] = fmaf(hv, wv.x, acc[j4*4+0]);
        acc[j4*4+1] = fmaf(hv, wv.y, acc[j4*4+1]);
        acc[j4*4+2] = fmaf(hv, wv.z, acc[j4*4+2]);
        acc[j4*4+3] = fmaf(hv, wv.w, acc[j4*4+3]);
      }
    }
  }
  // xl2 padded fp16: [h*4+c], c==3 -> 0
  f16x8 hx[4];
#pragma unroll
  for (int q = 0; q < 4; ++q) {          // q covers heads 2q, 2q+1
#pragma unroll
    for (int hh = 0; hh < 2; ++hh) {
      int hd = q * 2 + hh;
#pragma unroll
      for (int c = 0; c < 4; ++c)
        hx[q][hh * 4 + c] = (c < 3) ? (_Float16)acc[hd * 3 + c] : (_Float16)0.f;
    }
    *(f16x8*)(xl2p + (size_t)node * 32 + q * 8) = hx[q];
  }
  float4* rp = (float4*)(xr2 + (size_t)node * HC2);
#pragma unroll
  for (int j4 = 0; j4 < 6; ++j4)
    rp[j4] = make_float4(acc[24+j4*4+0], acc[24+j4*4+1], acc[24+j4*4+2], acc[24+j4*4+3]);
}

// ---------------- layer-2 edge pass + head-mean + final softmax --------------
__global__ __launch_bounds__(256) void k_edge2(const _Float16* __restrict__ xl2p,
    const float* __restrict__ xr2, const float* __restrict__ att2,
    const float* __restrict__ b2, const int* __restrict__ rowptr,
    const int* __restrict__ esrc, float* __restrict__ out) {
  int t = blockIdx.x * blockDim.x + threadIdx.x;   // exact grid: N*8
  int node = t >> 3, h = t & 7;
  float xrv[3], av[3];
#pragma unroll
  for (int c = 0; c < 3; ++c) {
    xrv[c] = xr2[(size_t)node * HC2 + h * NCLS + c];
    av[c]  = att2[h * NCLS + c];
  }
  float m = -INFINITY, s = 0.f;
  float acc[3] = {0.f, 0.f, 0.f};

  auto process = [&](const float* v) {
    float logit = 0.f;
#pragma unroll
    for (int c = 0; c < 3; ++c) {
      float u = v[c] + xrv[c];
      u = (u > 0.f) ? u : NEG * u;
      logit = fmaf(u, av[c], logit);
    }
    float mn = fmaxf(m, logit);
    float so = __expf(m - mn);
    float p  = __expf(logit - mn);
    s = s * so + p;
#pragma unroll
    for (int c = 0; c < 3; ++c) acc[c] = fmaf(acc[c], so, p * v[c]);
    m = mn;
  };

  int beg = rowptr[node], end = rowptr[node + 1];
  int i = beg;
  for (; i + 1 < end; i += 2) {
    int sn0 = esrc[i], sn1 = esrc[i + 1];
    if ((unsigned)sn0 >= N_NODES) sn0 = node;
    if ((unsigned)sn1 >= N_NODES) sn1 = node;
    f16x4 q0 = *(const f16x4*)(xl2p + (size_t)sn0 * 32 + h * 4);  // 8B
    f16x4 q1 = *(const f16x4*)(xl2p + (size_t)sn1 * 32 + h * 4);
    float v0[3] = {(float)q0[0], (float)q0[1], (float)q0[2]};
    float v1[3] = {(float)q1[0], (float)q1[1], (float)q1[2]};
    process(v0); process(v1);
  }
  if (i < end) {
    int sn0 = esrc[i];
    if ((unsigned)sn0 >= N_NODES) sn0 = node;
    f16x4 q0 = *(const f16x4*)(xl2p + (size_t)sn0 * 32 + h * 4);
    float v0[3] = {(float)q0[0], (float)q0[1], (float)q0[2]};
    process(v0);
  }

  float inv = (s > 0.f) ? 1.f / s : 0.f;
  float o[3];
#pragma unroll
  for (int c = 0; c < 3; ++c) o[c] = acc[c] * inv;
  // mean over 8 heads (8-lane group butterfly; grid exact so all lanes live)
#pragma unroll
  for (int off = 1; off < 8; off <<= 1) {
#pragma unroll
    for (int c = 0; c < 3; ++c) o[c] += __shfl_xor(o[c], off);
  }
  if (h < 3) {
    float z[3];
#pragma unroll
    for (int c = 0; c < 3; ++c) z[c] = o[c] * 0.125f + b2[c];
    float mx = fmaxf(fmaxf(z[0], z[1]), z[2]);
    float e0 = __expf(z[0] - mx), e1 = __expf(z[1] - mx), e2 = __expf(z[2] - mx);
    float sum = e0 + e1 + e2;
    float num = (h == 0) ? e0 : (h == 1) ? e1 : e2;
    out[(size_t)node * NCLS + h] = num / sum;
  }
}

// ---------------- launch -----------------------------------------------------
extern "C" void kernel_launch(void* const* d_in, const int* in_sizes, int n_in,
                              void* d_out, int out_size, void* d_ws, size_t ws_size,
                              hipStream_t stream) {
  (void)in_sizes; (void)n_in; (void)out_size; (void)ws_size;
  const float* x    = (const float*)d_in[0];
  const int*   ei   = (const int*)d_in[1];
  const float* W1l  = (const float*)d_in[2];
  const float* W1r  = (const float*)d_in[3];
  const float* att1 = (const float*)d_in[4];
  const float* b1   = (const float*)d_in[5];
  const float* W2l  = (const float*)d_in[6];
  const float* W2r  = (const float*)d_in[7];
  const float* att2 = (const float*)d_in[8];
  const float* b2   = (const float*)d_in[9];
  float* out = (float*)d_out;

  char* w = (char*)d_ws;
  _Float16* xl1h = (_Float16*)(w);             // 12.8 MB (bstage overlays pre-gemm1)
  float* xr1  = (float*)(w + 12800000);        // 25.6 MB -> ends 38.4M
  float* hbuf = (float*)(w + 38400000);        // 25.6 MB -> ends 64.0M
  _Float16* Wimg = (_Float16*)(w + 64000000);  // 128 KB
  _Float16* xl2p = (_Float16*)(w);             // 6.4 MB (xl1h dead after edge1)
  float* xr2  = (float*)(w + 6400000);         // 9.6 MB (inside dead xl1h/xr1)
  unsigned* bstage = (unsigned*)(w);           // 6.8 MB, dead before gemm1
  char* ip = w + 76800000;
  int* rowptr = (int*)(ip);                    // 400,004 B
  int* cmat   = (int*)(ip + 400128);           // 425,984 B
  int* bbase  = (int*)(ip + 826112);           // 1,028 B
  int* flag   = (int*)(ip + 827392);           // 4 B
  int* esrc   = (int*)(ip + 827648);           // 6.8 MB

  hipMemsetAsync(flag, 0, 4, stream);

  k_detect <<<16, 256, 0, stream>>>(ei, flag);
  k_wconv  <<<256, 256, 0, stream>>>(W1l, W1r, Wimg);
  k_cntA   <<<NCHUNK, 256, 0, stream>>>(ei, flag, cmat);
  k_scanA  <<<1, NBUCK, 0, stream>>>(cmat, bbase, rowptr);
  k_grpA   <<<NCHUNK, 256, 0, stream>>>(ei, flag, cmat, bbase, bstage);
  k_partB  <<<NBUCK, 256, 0, stream>>>(bstage, bbase, rowptr, esrc);
  k_gemm1  <<<NBLK, 512, 0, stream>>>(x, (const uint4*)Wimg, xl1h, xr1);
  k_edge1  <<<(N_NODES * HEADS) / 256, 256, 0, stream>>>(xl1h, xr1, att1, b1, rowptr, esrc, hbuf);
  k_gemm2  <<<(N_NODES + 255) / 256, 256, 0, stream>>>(hbuf, W2l, W2r, xl2p, xr2);
  k_edge2  <<<(N_NODES * HEADS) / 256, 256, 0, stream>>>(xl2p, xr2, att2, b2, rowptr, esrc, out);
}